// Round 11
// baseline (349.132 us; speedup 1.0000x reference)
//
#include <hip/hip_runtime.h>
#include <hip/hip_bf16.h>

#define T_ 4
#define C_ 64
#define H_ 128
#define W_ 128
#define CI_ 16
#define PS_ 7
#define NC_ 729       // 27*27 candidates per query
#define S0_ 4
#define KS_ 100
#define NQ_ 1024      // 32*32 queries per frame
#define SCALE_ 10.0f
#define HW_ (H_*W_)
#define RW_ 45        // 4x4-tile region dim (float4); 45%8=5 -> bank rotation
#define LCAP_ 768

typedef float v2f __attribute__((ext_vector_type(2)));
#if __has_builtin(__builtin_elementwise_fma)
#define VFMA(a, b, c) __builtin_elementwise_fma((a), (b), (c))
#else
#define VFMA(a, b, c) ((a) * (b) + (c))
#endif

// ---------------- conv 3x3, 64->16, 2px/thread, dwordx4 row loads -----------
// Grid (32, 4, T): tile 32x16, co-group g of 4 = output chunk g.
__device__ __forceinline__ float4 ldrow3(const float* p, int row, int c0,
                                         bool rok, bool fast) {
  float4 r = make_float4(0.f, 0.f, 0.f, 0.f);
  if (!rok) return r;
  const float* rp = p + row * W_;
  if (fast) {
    r = *(const float4*)(rp + c0);
  } else {
    if (c0 >= 0) r.x = rp[c0];
    if (c0 + 1 >= 0 && c0 + 1 < W_) r.y = rp[c0 + 1];
    if (c0 + 2 < W_) r.z = rp[c0 + 2];
    if (c0 + 3 < W_) r.w = rp[c0 + 3];
  }
  return r;
}

__global__ __launch_bounds__(256) void conv3x3_kernel(
    const float* __restrict__ vid, const float* __restrict__ gw,
    const float* __restrict__ gb, float4* __restrict__ v1cs) {
  __shared__ float wls[C_ * 9 * 4];   // [c][k][co]
  const int tid = threadIdx.x;
  const int g = blockIdx.y, t = blockIdx.z;
  for (int m = tid; m < C_ * 9 * 4; m += 256) {
    int co = m & 3, ck = m >> 2;
    wls[m] = gw[((size_t)(g * 4 + co) * C_) * 9 + ck];
  }
  __syncthreads();
  const int tj0 = (blockIdx.x & 3) * 32, ti0 = (blockIdx.x >> 2) * 16;
  const int u = tid >> 4, v = tid & 15;
  const int i = ti0 + u, j0 = tj0 + 2 * v;
  const int c0 = j0 - 1;
  const bool fast = (c0 >= 0) && (c0 + 3 < W_);
  const bool rok0 = (i - 1 >= 0), rok2 = (i + 1 < H_);

  float accA[4], accB[4];
#pragma unroll
  for (int co = 0; co < 4; ++co) { accA[co] = gb[g * 4 + co]; accB[co] = gb[g * 4 + co]; }

  const float* vb = vid + ((size_t)t * C_) * HW_;
#pragma unroll 2
  for (int c = 0; c < C_; ++c) {
    const float* p = vb + (size_t)c * HW_;
    float4 r0 = ldrow3(p, i - 1, c0, rok0, fast);
    float4 r1 = ldrow3(p, i,     c0, true, fast);
    float4 r2 = ldrow3(p, i + 1, c0, rok2, fast);
    const float* wc = &wls[c * 36];   // [k][co]
    float e0[4] = {r0.x, r0.y, r0.z, r0.w};
    float e1[4] = {r1.x, r1.y, r1.z, r1.w};
    float e2[4] = {r2.x, r2.y, r2.z, r2.w};
#pragma unroll
    for (int kj = 0; kj < 3; ++kj) {
#pragma unroll
      for (int co = 0; co < 4; ++co) {
        accA[co] = fmaf(wc[(0 * 3 + kj) * 4 + co], e0[kj],     accA[co]);
        accB[co] = fmaf(wc[(0 * 3 + kj) * 4 + co], e0[kj + 1], accB[co]);
        accA[co] = fmaf(wc[(1 * 3 + kj) * 4 + co], e1[kj],     accA[co]);
        accB[co] = fmaf(wc[(1 * 3 + kj) * 4 + co], e1[kj + 1], accB[co]);
        accA[co] = fmaf(wc[(2 * 3 + kj) * 4 + co], e2[kj],     accA[co]);
        accB[co] = fmaf(wc[(2 * 3 + kj) * 4 + co], e2[kj + 1], accB[co]);
      }
    }
  }
  const size_t o = ((size_t)g * T_ + t) * HW_ + i * W_ + j0;
  v1cs[o]     = make_float4(accA[0], accA[1], accA[2], accA[3]);
  v1cs[o + 1] = make_float4(accB[0], accB[1], accB[2], accB[3]);
}

// ---------------- conv 1x1, 64->16, chunk-major float4 output ----------------
__global__ __launch_bounds__(256) void conv1x1_kernel(
    const float* __restrict__ vid, const float* __restrict__ tw,
    const float* __restrict__ tb, float4* __restrict__ v2cs) {
  __shared__ float w[C_ * 4];
  const int t = blockIdx.y, cc = blockIdx.z;
  for (int m = threadIdx.x; m < C_ * 4; m += 256) {
    int o = m & 3, c = m >> 2;
    w[m] = tw[(cc * 4 + o) * C_ + c];
  }
  __syncthreads();
  const int pix = blockIdx.x * 256 + threadIdx.x;
  float acc[4];
#pragma unroll
  for (int o = 0; o < 4; ++o) acc[o] = tb[cc * 4 + o];
  const float* vb = vid + ((size_t)t * C_) * HW_ + pix;
#pragma unroll 1
  for (int c0 = 0; c0 < C_; c0 += 8) {
    float x[8];
#pragma unroll
    for (int uu = 0; uu < 8; ++uu) x[uu] = vb[(size_t)(c0 + uu) * HW_];
#pragma unroll
    for (int uu = 0; uu < 8; ++uu)
#pragma unroll
      for (int o = 0; o < 4; ++o)
        acc[o] = fmaf(w[(c0 + uu) * 4 + o], x[uu], acc[o]);
  }
  v2cs[((size_t)cc * T_ + t) * HW_ + pix] = make_float4(acc[0], acc[1], acc[2], acc[3]);
}

// ---------------- dists: 4x4-query tile, packed v_pk_fma_f32 accumulators ---
__global__ __launch_bounds__(1024) void dist_kernel(
    const float4* __restrict__ v1cs, float* __restrict__ distG) {
  __shared__ float4 Rs[RW_ * RW_];
  const int tid = threadIdx.x;
  const int t = blockIdx.y;
  const int qi0 = (blockIdx.x >> 3) * 16, qj0 = (blockIdx.x & 7) * 16;
  const int w = tid >> 6, lane = tid & 63;
  const int di = (w >> 2) * 4, dj = (w & 3) * 4;
  const int qi = qi0 + di, qj = qj0 + dj;
  const int a_lo = max(13 - qi, 0), b_lo = max(13 - qj, 0);
  const int ai = lane >> 1, bg = lane & 1;
  const bool active = ai < 27;
  const int a = min(a_lo + ai, 26);
  const int bs = bg ? 13 : b_lo;

  v2f acc2[14];
#pragma unroll
  for (int j = 0; j < 14; ++j) acc2[j] = (v2f){0.f, 0.f};

#pragma unroll 1
  for (int cc = 0; cc < 4; ++cc) {
    __syncthreads();
    const float4* src = v1cs + ((size_t)cc * T_ + t) * HW_;
    for (int p = tid; p < RW_ * RW_; p += 1024) {
      int uu = p / RW_, vv = p - uu * RW_;
      int row = min(max(qi0 - 13 + uu, 0), H_ - 1);
      int col = min(max(qj0 - 13 + vv, 0), W_ - 1);
      Rs[p] = src[row * W_ + col];
    }
    __syncthreads();
    if (active) {
#pragma unroll 1
      for (int r = 0; r < 7; ++r) {
        v2f qlo[7], qhi[7];
        const float4* qrow = &Rs[(di + 13 + r) * RW_ + dj + 13];
#pragma unroll
        for (int s = 0; s < 7; ++s) {
          float4 qq = qrow[s];
          qlo[s] = (v2f){qq.x, qq.y};
          qhi[s] = (v2f){qq.z, qq.w};
        }
        const float4* crow = &Rs[(di + a + r) * RW_ + dj + bs];
#pragma unroll
        for (int y = 0; y < 20; ++y) {
          float4 vv = crow[y];
          v2f vlo = (v2f){vv.x, vv.y}, vhi = (v2f){vv.z, vv.w};
          const int s_lo = (y > 13) ? (y - 13) : 0;
          const int s_hi = (y < 6) ? y : 6;
#pragma unroll
          for (int s = s_lo; s <= s_hi; ++s) {
            int j = y - s;
            acc2[j] = VFMA(qlo[s], vlo, acc2[j]);
            acc2[j] = VFMA(qhi[s], vhi, acc2[j]);
          }
        }
      }
    }
  }
  if (active) {
    const int q = ((qi >> 2) << 5) + (qj >> 2);
    float* out = distG + ((size_t)t * NQ_ + q) * NC_ + a * 27 + bs;
#pragma unroll
    for (int j = 0; j < 14; ++j) out[j] = acc2[j].x + acc2[j].y;
  }
}

// ---------------- select: 2-level radix top-100, wave-primitive scans -------
__global__ __launch_bounds__(256) void select_kernel(
    const float* __restrict__ distG, int* __restrict__ sel_n,
    float* __restrict__ sel_w, float* __restrict__ wsum_out) {
  __shared__ float dist[NC_];
  __shared__ unsigned int ukey[NC_];
  __shared__ float redf[4];
  __shared__ unsigned int hist[256];
  __shared__ int lk[LCAP_];
  __shared__ unsigned int lkey[LCAP_];
  __shared__ unsigned int scal[6];   // 0=beta 1=run 2=cursor 3=listlen 4=beta2 5=run2

  const int tid = threadIdx.x;
  const int lane = tid & 63, wid = tid >> 6;
  const int q = blockIdx.x, t = blockIdx.y;
  const int qi = (q >> 5) * S0_, qj = (q & 31) * S0_;
  const int a_lo = max(13 - qi, 0), b_lo = max(13 - qj, 0);
  const size_t base = ((size_t)t * NQ_ + q) * NC_;

  for (int h = tid; h < 256; h += 256) hist[h] = 0;
  if (tid == 0) { scal[2] = 0; scal[3] = 0; }
  float lmax = -INFINITY;
  for (int k = tid; k < NC_; k += 256) {
    int aa = k / 27, bb = k - aa * 27;
    int kk = max(aa, a_lo) * 27 + max(bb, b_lo);
    float d = distG[base + kk];
    dist[k] = d;
    unsigned int u = __float_as_uint(d);
    ukey[k] = u ^ (((unsigned int)((int)u >> 31)) | 0x80000000u);
    lmax = fmaxf(lmax, d);
  }
#pragma unroll
  for (int off = 32; off > 0; off >>= 1)
    lmax = fmaxf(lmax, __shfl_down(lmax, off, 64));
  if (lane == 0) redf[wid] = lmax;
  __syncthreads();                                             // B1
  const float dmax = fmaxf(fmaxf(redf[0], redf[1]), fmaxf(redf[2], redf[3]));
  for (int k = tid; k < NC_; k += 256) atomicAdd(&hist[ukey[k] >> 24], 1u);
  __syncthreads();                                             // B2
  if (wid == 0) {
    int s4 = (int)(hist[lane * 4] + hist[lane * 4 + 1] + hist[lane * 4 + 2] + hist[lane * 4 + 3]);
    int s = s4;
#pragma unroll
    for (int off = 1; off < 64; off <<= 1) {
      int o = __shfl_down(s, off, 64);
      if (lane + off < 64) s += o;
    }
    int above = s - s4;
    if (above < KS_ && s >= KS_) {
      int run = above;
#pragma unroll
      for (int bb = 3; bb >= 0; --bb) {
        int h = (int)hist[lane * 4 + bb];
        if (run + h >= KS_) { scal[0] = (unsigned int)(lane * 4 + bb); scal[1] = (unsigned int)run; break; }
        run += h;
      }
    }
  }
  __syncthreads();                                             // B3
  const unsigned int beta = scal[0];
  const int run = (int)scal[1];
  for (int h = tid; h < 256; h += 256) hist[h] = 0;
  __syncthreads();                                             // B4
  for (int k = tid; k < NC_; k += 256)
    if ((ukey[k] >> 24) == beta) atomicAdd(&hist[(ukey[k] >> 16) & 0xFFu], 1u);
  __syncthreads();                                             // B5
  if (wid == 0) {
    int s4 = (int)(hist[lane * 4] + hist[lane * 4 + 1] + hist[lane * 4 + 2] + hist[lane * 4 + 3]);
    int s = s4;
#pragma unroll
    for (int off = 1; off < 64; off <<= 1) {
      int o = __shfl_down(s, off, 64);
      if (lane + off < 64) s += o;
    }
    int above = run + s - s4;
    if (above < KS_ && run + s >= KS_) {
      int r2 = above;
#pragma unroll
      for (int bb = 3; bb >= 0; --bb) {
        int h = (int)hist[lane * 4 + bb];
        if (r2 + h >= KS_) { scal[4] = (unsigned int)(lane * 4 + bb); scal[5] = (unsigned int)r2; break; }
        r2 += h;
      }
    }
  }
  __syncthreads();                                             // B6
  const unsigned int beta2 = scal[4];
  const int run2 = (int)scal[5];
  const size_t outb = ((size_t)t * NQ_ + q) * KS_;
  float lsum = 0.f;
  for (int k = tid; k < NC_; k += 256) {
    unsigned int key = ukey[k];
    unsigned int bin = key >> 24;
    bool sel = false, bdry = false;
    if (bin > beta) sel = true;
    else if (bin == beta) {
      unsigned int b2 = (key >> 16) & 0xFFu;
      if (b2 > beta2) sel = true;
      else if (b2 == beta2) bdry = true;
    }
    if (sel) {
      unsigned int slot = atomicAdd(&scal[2], 1u);
      int aa = k / 27, bb = k - aa * 27;
      int ni = min(max(qi + aa - 13, 0), H_ - 1);
      int nj = min(max(qj + bb - 13, 0), W_ - 1);
      float wv = __expf(SCALE_ * (dist[k] - dmax));
      sel_n[outb + slot] = (ni << 7) | nj;
      sel_w[outb + slot] = wv;
      lsum += wv;
    } else if (bdry) {
      unsigned int pos = atomicAdd(&scal[3], 1u);
      if (pos < LCAP_) { lk[pos] = k; lkey[pos] = key; }
    }
  }
  __syncthreads();                                             // B7
  const int L = min((int)scal[3], LCAP_);
  for (int i = tid; i < L; i += 256) {
    unsigned int key = lkey[i];
    int k = lk[i];
    int cnt = run2;
    for (int m = 0; m < L; ++m)
      cnt += (int)((lkey[m] > key) || (lkey[m] == key && lk[m] < k));
    if (cnt < KS_) {
      unsigned int slot = atomicAdd(&scal[2], 1u);
      int aa = k / 27, bb = k - aa * 27;
      int ni = min(max(qi + aa - 13, 0), H_ - 1);
      int nj = min(max(qj + bb - 13, 0), W_ - 1);
      float wv = __expf(SCALE_ * (dist[k] - dmax));
      sel_n[outb + slot] = (ni << 7) | nj;
      sel_w[outb + slot] = wv;
      lsum += wv;
    }
  }
#pragma unroll
  for (int off = 32; off > 0; off >>= 1) lsum += __shfl_down(lsum, off, 64);
  __syncthreads();                                             // B8
  if (lane == 0) redf[wid] = lsum;
  __syncthreads();                                             // B9
  if (tid == 0) wsum_out[t * NQ_ + q] = (redf[0] + redf[1]) + (redf[2] + redf[3]);
}

// ---------------- weighted aggregation + fold (direct L2 gather) ------------
__global__ __launch_bounds__(256) void agg_kernel(
    const float4* __restrict__ v2cs, const int* __restrict__ sel_n,
    const float* __restrict__ sel_w, const float* __restrict__ wsum,
    float* __restrict__ Y) {
  __shared__ int s_ni[KS_], s_nj[KS_];
  __shared__ float s_w[KS_];
  const int tid = threadIdx.x;
  const int q = blockIdx.x, t = blockIdx.y;
  const int qi = (q >> 5) * S0_, qj = (q & 31) * S0_;
  const size_t base = ((size_t)t * NQ_ + q) * KS_;
  if (tid < KS_) {
    int n = sel_n[base + tid];
    s_ni[tid] = n >> 7;
    s_nj[tid] = n & 127;
    s_w[tid] = sel_w[base + tid] / wsum[t * NQ_ + q];
  }
  __syncthreads();
  const int cc = tid >> 6, lane = tid & 63;
  if (lane >= 49) return;
  const int r = lane / 7, s = lane - r * 7;
  const float4* src = v2cs + ((size_t)cc * T_ + t) * HW_;
  float4 acc = make_float4(0.f, 0.f, 0.f, 0.f);
#pragma unroll 4
  for (int k = 0; k < KS_; ++k) {
    int ri = min(s_ni[k] + r, H_ - 1);
    int ci = min(s_nj[k] + s, W_ - 1);
    float4 v = src[ri * W_ + ci];
    float w = s_w[k];
    acc.x = fmaf(w, v.x, acc.x);
    acc.y = fmaf(w, v.y, acc.y);
    acc.z = fmaf(w, v.z, acc.z);
    acc.w = fmaf(w, v.w, acc.w);
  }
  const int oi = min(qi + r, H_ - 1), oj = min(qj + s, W_ - 1);
  float* yb = Y + (((size_t)t * CI_ + cc * 4) * H_ + oi) * W_ + oj;
  atomicAdd(yb, acc.x);
  atomicAdd(yb + HW_, acc.y);
  atomicAdd(yb + 2 * HW_, acc.z);
  atomicAdd(yb + 3 * HW_, acc.w);
}

// ---------------- normalize by analytic fold counts -------------------------
__device__ __forceinline__ int cov_axis(int x) {
  int c = 0;
#pragma unroll
  for (int r = 0; r < 7; ++r) {
    if (x < H_ - 1) {
      int qb = x - r;
      c += (qb >= 0 && (qb & 3) == 0) ? 1 : 0;
    } else {
      c += (r >= 3) ? 1 : 0;
    }
  }
  return c;
}

__global__ void norm_kernel(float* __restrict__ Y) {
  int idx = blockIdx.x * blockDim.x + threadIdx.x;
  if (idx >= T_ * CI_ * HW_) return;
  int p = idx & (HW_ - 1);
  float z = (float)(cov_axis(p >> 7) * cov_axis(p & 127));
  Y[idx] /= z;
}

extern "C" void kernel_launch(void* const* d_in, const int* in_sizes, int n_in,
                              void* d_out, int out_size, void* d_ws, size_t ws_size,
                              hipStream_t stream) {
  const float* vid     = (const float*)d_in[0];
  const float* g_w     = (const float*)d_in[1];
  const float* g_b     = (const float*)d_in[2];
  const float* theta_w = (const float*)d_in[3];
  const float* theta_b = (const float*)d_in[4];
  float* Y = (float*)d_out;

  // workspace (floats): v1cs | v2cs | distG | sel_n | sel_w | wsum  (~24 MB)
  float* v1cs  = (float*)d_ws;
  float* v2cs  = v1cs + (size_t)4 * T_ * HW_ * 4;              // 1048576
  float* distG = v2cs + (size_t)4 * T_ * HW_ * 4;              // 1048576
  int*   sel_n = (int*)(distG + (size_t)T_ * NQ_ * NC_);       // 2985984
  float* sel_w = (float*)(sel_n + (size_t)T_ * NQ_ * KS_);     // 409600
  float* wsumv = sel_w + (size_t)T_ * NQ_ * KS_;               // 409600

  hipMemsetAsync(Y, 0, (size_t)out_size * sizeof(float), stream);

  conv3x3_kernel<<<dim3(32, 4, T_), 256, 0, stream>>>(vid, g_w, g_b, (float4*)v1cs);
  conv1x1_kernel<<<dim3(HW_ / 256, T_, 4), 256, 0, stream>>>(vid, theta_w, theta_b, (float4*)v2cs);
  dist_kernel<<<dim3(64, T_), 1024, 0, stream>>>((const float4*)v1cs, distG);
  select_kernel<<<dim3(NQ_, T_), 256, 0, stream>>>(distG, sel_n, sel_w, wsumv);
  agg_kernel<<<dim3(NQ_, T_), 256, 0, stream>>>((const float4*)v2cs, sel_n, sel_w, wsumv, Y);
  norm_kernel<<<(T_ * CI_ * HW_ + 255) / 256, 256, 0, stream>>>(Y);
}

// Round 12
// 341.932 us; speedup vs baseline: 1.0211x; 1.0211x over previous
//
#include <hip/hip_runtime.h>
#include <hip/hip_bf16.h>

#define T_ 4
#define C_ 64
#define H_ 128
#define W_ 128
#define CI_ 16
#define PS_ 7
#define NC_ 729       // 27*27 candidates per query
#define S0_ 4
#define KS_ 100
#define NQ_ 1024      // 32*32 queries per frame
#define SCALE_ 10.0f
#define HW_ (H_*W_)
#define RW_ 45        // 4x4-tile region dim (float4); 45%8=5 -> bank rotation
#define LCAP_ 768
#define CB_ 8         // conv3x3 channel batch (24 dwordx4 in flight)

typedef float v2f __attribute__((ext_vector_type(2)));
#if __has_builtin(__builtin_elementwise_fma)
#define VFMA(a, b, c) __builtin_elementwise_fma((a), (b), (c))
#else
#define VFMA(a, b, c) ((a) * (b) + (c))
#endif

// ---------------- conv 3x3, 64->16, 2px/thread, 8-channel load batches ------
// Grid (64, 4, T): 16x16 tile, 128 threads, co-group g of 4 = output chunk g.
// 24 independent dwordx4 loads in flight per thread -> latency hiding via MLP.
__device__ __forceinline__ float4 ldrow3(const float* p, int row, int c0,
                                         bool rok, bool fast) {
  float4 r = make_float4(0.f, 0.f, 0.f, 0.f);
  if (!rok) return r;
  const float* rp = p + row * W_;
  if (fast) {
    r = *(const float4*)(rp + c0);
  } else {
    if (c0 >= 0) r.x = rp[c0];
    if (c0 + 1 >= 0 && c0 + 1 < W_) r.y = rp[c0 + 1];
    if (c0 + 2 < W_) r.z = rp[c0 + 2];
    if (c0 + 3 < W_) r.w = rp[c0 + 3];
  }
  return r;
}

__global__ __launch_bounds__(128) void conv3x3_kernel(
    const float* __restrict__ vid, const float* __restrict__ gw,
    const float* __restrict__ gb, float4* __restrict__ v1cs) {
  __shared__ float wls[C_ * 9 * 4];   // [c][k][co]
  const int tid = threadIdx.x;
  const int g = blockIdx.y, t = blockIdx.z;
  for (int m = tid; m < C_ * 9 * 4; m += 128) {
    int co = m & 3, ck = m >> 2;
    wls[m] = gw[((size_t)(g * 4 + co) * C_) * 9 + ck];
  }
  __syncthreads();
  const int ti0 = (blockIdx.x >> 3) * 16, tj0 = (blockIdx.x & 7) * 16;
  const int u = tid >> 3, v = tid & 7;   // 16 rows x 8 col-pairs
  const int i = ti0 + u, j0 = tj0 + 2 * v;
  const int c0 = j0 - 1;
  const bool fast = (c0 >= 0) && (c0 + 3 < W_);
  const bool rok0 = (i - 1 >= 0), rok2 = (i + 1 < H_);

  float accA[4], accB[4];
#pragma unroll
  for (int co = 0; co < 4; ++co) { accA[co] = gb[g * 4 + co]; accB[co] = gb[g * 4 + co]; }

  const float* vb = vid + ((size_t)t * C_) * HW_;
#pragma unroll 1
  for (int cb = 0; cb < C_; cb += CB_) {
    float4 r[CB_][3];
#pragma unroll
    for (int c = 0; c < CB_; ++c) {       // 24 independent loads issued first
      const float* p = vb + (size_t)(cb + c) * HW_;
      r[c][0] = ldrow3(p, i - 1, c0, rok0, fast);
      r[c][1] = ldrow3(p, i,     c0, true, fast);
      r[c][2] = ldrow3(p, i + 1, c0, rok2, fast);
    }
#pragma unroll
    for (int c = 0; c < CB_; ++c) {
      const float* wc = &wls[(cb + c) * 36];   // [k][co]
      float e0[4] = {r[c][0].x, r[c][0].y, r[c][0].z, r[c][0].w};
      float e1[4] = {r[c][1].x, r[c][1].y, r[c][1].z, r[c][1].w};
      float e2[4] = {r[c][2].x, r[c][2].y, r[c][2].z, r[c][2].w};
#pragma unroll
      for (int kj = 0; kj < 3; ++kj) {
#pragma unroll
        for (int co = 0; co < 4; ++co) {
          accA[co] = fmaf(wc[(0 * 3 + kj) * 4 + co], e0[kj],     accA[co]);
          accB[co] = fmaf(wc[(0 * 3 + kj) * 4 + co], e0[kj + 1], accB[co]);
          accA[co] = fmaf(wc[(1 * 3 + kj) * 4 + co], e1[kj],     accA[co]);
          accB[co] = fmaf(wc[(1 * 3 + kj) * 4 + co], e1[kj + 1], accB[co]);
          accA[co] = fmaf(wc[(2 * 3 + kj) * 4 + co], e2[kj],     accA[co]);
          accB[co] = fmaf(wc[(2 * 3 + kj) * 4 + co], e2[kj + 1], accB[co]);
        }
      }
    }
  }
  const size_t o = ((size_t)g * T_ + t) * HW_ + i * W_ + j0;
  v1cs[o]     = make_float4(accA[0], accA[1], accA[2], accA[3]);
  v1cs[o + 1] = make_float4(accB[0], accB[1], accB[2], accB[3]);
}

// ---------------- conv 1x1, 64->16, chunk-major float4 output ----------------
__global__ __launch_bounds__(256) void conv1x1_kernel(
    const float* __restrict__ vid, const float* __restrict__ tw,
    const float* __restrict__ tb, float4* __restrict__ v2cs) {
  __shared__ float w[C_ * 4];
  const int t = blockIdx.y, cc = blockIdx.z;
  for (int m = threadIdx.x; m < C_ * 4; m += 256) {
    int o = m & 3, c = m >> 2;
    w[m] = tw[(cc * 4 + o) * C_ + c];
  }
  __syncthreads();
  const int pix = blockIdx.x * 256 + threadIdx.x;
  float acc[4];
#pragma unroll
  for (int o = 0; o < 4; ++o) acc[o] = tb[cc * 4 + o];
  const float* vb = vid + ((size_t)t * C_) * HW_ + pix;
#pragma unroll 1
  for (int c0 = 0; c0 < C_; c0 += 8) {
    float x[8];
#pragma unroll
    for (int uu = 0; uu < 8; ++uu) x[uu] = vb[(size_t)(c0 + uu) * HW_];
#pragma unroll
    for (int uu = 0; uu < 8; ++uu)
#pragma unroll
      for (int o = 0; o < 4; ++o)
        acc[o] = fmaf(w[(c0 + uu) * 4 + o], x[uu], acc[o]);
  }
  v2cs[((size_t)cc * T_ + t) * HW_ + pix] = make_float4(acc[0], acc[1], acc[2], acc[3]);
}

// ---------------- dists: 4x4-query tile, packed v_pk_fma_f32 accumulators ---
__global__ __launch_bounds__(1024) void dist_kernel(
    const float4* __restrict__ v1cs, float* __restrict__ distG) {
  __shared__ float4 Rs[RW_ * RW_];
  const int tid = threadIdx.x;
  const int t = blockIdx.y;
  const int qi0 = (blockIdx.x >> 3) * 16, qj0 = (blockIdx.x & 7) * 16;
  const int w = tid >> 6, lane = tid & 63;
  const int di = (w >> 2) * 4, dj = (w & 3) * 4;
  const int qi = qi0 + di, qj = qj0 + dj;
  const int a_lo = max(13 - qi, 0), b_lo = max(13 - qj, 0);
  const int ai = lane >> 1, bg = lane & 1;
  const bool active = ai < 27;
  const int a = min(a_lo + ai, 26);
  const int bs = bg ? 13 : b_lo;

  v2f acc2[14];
#pragma unroll
  for (int j = 0; j < 14; ++j) acc2[j] = (v2f){0.f, 0.f};

#pragma unroll 1
  for (int cc = 0; cc < 4; ++cc) {
    __syncthreads();
    const float4* src = v1cs + ((size_t)cc * T_ + t) * HW_;
    for (int p = tid; p < RW_ * RW_; p += 1024) {
      int uu = p / RW_, vv = p - uu * RW_;
      int row = min(max(qi0 - 13 + uu, 0), H_ - 1);
      int col = min(max(qj0 - 13 + vv, 0), W_ - 1);
      Rs[p] = src[row * W_ + col];
    }
    __syncthreads();
    if (active) {
#pragma unroll 1
      for (int r = 0; r < 7; ++r) {
        v2f qlo[7], qhi[7];
        const float4* qrow = &Rs[(di + 13 + r) * RW_ + dj + 13];
#pragma unroll
        for (int s = 0; s < 7; ++s) {
          float4 qq = qrow[s];
          qlo[s] = (v2f){qq.x, qq.y};
          qhi[s] = (v2f){qq.z, qq.w};
        }
        const float4* crow = &Rs[(di + a + r) * RW_ + dj + bs];
#pragma unroll
        for (int y = 0; y < 20; ++y) {
          float4 vv = crow[y];
          v2f vlo = (v2f){vv.x, vv.y}, vhi = (v2f){vv.z, vv.w};
          const int s_lo = (y > 13) ? (y - 13) : 0;
          const int s_hi = (y < 6) ? y : 6;
#pragma unroll
          for (int s = s_lo; s <= s_hi; ++s) {
            int j = y - s;
            acc2[j] = VFMA(qlo[s], vlo, acc2[j]);
            acc2[j] = VFMA(qhi[s], vhi, acc2[j]);
          }
        }
      }
    }
  }
  if (active) {
    const int q = ((qi >> 2) << 5) + (qj >> 2);
    float* out = distG + ((size_t)t * NQ_ + q) * NC_ + a * 27 + bs;
#pragma unroll
    for (int j = 0; j < 14; ++j) out[j] = acc2[j].x + acc2[j].y;
  }
}

// ---------------- select: 2-level radix top-100, wave-primitive scans -------
__global__ __launch_bounds__(256) void select_kernel(
    const float* __restrict__ distG, int* __restrict__ sel_n,
    float* __restrict__ sel_w, float* __restrict__ wsum_out) {
  __shared__ float dist[NC_];
  __shared__ unsigned int ukey[NC_];
  __shared__ float redf[4];
  __shared__ unsigned int hist[256];
  __shared__ int lk[LCAP_];
  __shared__ unsigned int lkey[LCAP_];
  __shared__ unsigned int scal[6];   // 0=beta 1=run 2=cursor 3=listlen 4=beta2 5=run2

  const int tid = threadIdx.x;
  const int lane = tid & 63, wid = tid >> 6;
  const int q = blockIdx.x, t = blockIdx.y;
  const int qi = (q >> 5) * S0_, qj = (q & 31) * S0_;
  const int a_lo = max(13 - qi, 0), b_lo = max(13 - qj, 0);
  const size_t base = ((size_t)t * NQ_ + q) * NC_;

  for (int h = tid; h < 256; h += 256) hist[h] = 0;
  if (tid == 0) { scal[2] = 0; scal[3] = 0; }
  float lmax = -INFINITY;
  for (int k = tid; k < NC_; k += 256) {
    int aa = k / 27, bb = k - aa * 27;
    int kk = max(aa, a_lo) * 27 + max(bb, b_lo);
    float d = distG[base + kk];
    dist[k] = d;
    unsigned int u = __float_as_uint(d);
    ukey[k] = u ^ (((unsigned int)((int)u >> 31)) | 0x80000000u);
    lmax = fmaxf(lmax, d);
  }
#pragma unroll
  for (int off = 32; off > 0; off >>= 1)
    lmax = fmaxf(lmax, __shfl_down(lmax, off, 64));
  if (lane == 0) redf[wid] = lmax;
  __syncthreads();                                             // B1
  const float dmax = fmaxf(fmaxf(redf[0], redf[1]), fmaxf(redf[2], redf[3]));
  for (int k = tid; k < NC_; k += 256) atomicAdd(&hist[ukey[k] >> 24], 1u);
  __syncthreads();                                             // B2
  if (wid == 0) {
    int s4 = (int)(hist[lane * 4] + hist[lane * 4 + 1] + hist[lane * 4 + 2] + hist[lane * 4 + 3]);
    int s = s4;
#pragma unroll
    for (int off = 1; off < 64; off <<= 1) {
      int o = __shfl_down(s, off, 64);
      if (lane + off < 64) s += o;
    }
    int above = s - s4;
    if (above < KS_ && s >= KS_) {
      int run = above;
#pragma unroll
      for (int bb = 3; bb >= 0; --bb) {
        int h = (int)hist[lane * 4 + bb];
        if (run + h >= KS_) { scal[0] = (unsigned int)(lane * 4 + bb); scal[1] = (unsigned int)run; break; }
        run += h;
      }
    }
  }
  __syncthreads();                                             // B3
  const unsigned int beta = scal[0];
  const int run = (int)scal[1];
  for (int h = tid; h < 256; h += 256) hist[h] = 0;
  __syncthreads();                                             // B4
  for (int k = tid; k < NC_; k += 256)
    if ((ukey[k] >> 24) == beta) atomicAdd(&hist[(ukey[k] >> 16) & 0xFFu], 1u);
  __syncthreads();                                             // B5
  if (wid == 0) {
    int s4 = (int)(hist[lane * 4] + hist[lane * 4 + 1] + hist[lane * 4 + 2] + hist[lane * 4 + 3]);
    int s = s4;
#pragma unroll
    for (int off = 1; off < 64; off <<= 1) {
      int o = __shfl_down(s, off, 64);
      if (lane + off < 64) s += o;
    }
    int above = run + s - s4;
    if (above < KS_ && run + s >= KS_) {
      int r2 = above;
#pragma unroll
      for (int bb = 3; bb >= 0; --bb) {
        int h = (int)hist[lane * 4 + bb];
        if (r2 + h >= KS_) { scal[4] = (unsigned int)(lane * 4 + bb); scal[5] = (unsigned int)r2; break; }
        r2 += h;
      }
    }
  }
  __syncthreads();                                             // B6
  const unsigned int beta2 = scal[4];
  const int run2 = (int)scal[5];
  const size_t outb = ((size_t)t * NQ_ + q) * KS_;
  float lsum = 0.f;
  for (int k = tid; k < NC_; k += 256) {
    unsigned int key = ukey[k];
    unsigned int bin = key >> 24;
    bool sel = false, bdry = false;
    if (bin > beta) sel = true;
    else if (bin == beta) {
      unsigned int b2 = (key >> 16) & 0xFFu;
      if (b2 > beta2) sel = true;
      else if (b2 == beta2) bdry = true;
    }
    if (sel) {
      unsigned int slot = atomicAdd(&scal[2], 1u);
      int aa = k / 27, bb = k - aa * 27;
      int ni = min(max(qi + aa - 13, 0), H_ - 1);
      int nj = min(max(qj + bb - 13, 0), W_ - 1);
      float wv = __expf(SCALE_ * (dist[k] - dmax));
      sel_n[outb + slot] = (ni << 7) | nj;
      sel_w[outb + slot] = wv;
      lsum += wv;
    } else if (bdry) {
      unsigned int pos = atomicAdd(&scal[3], 1u);
      if (pos < LCAP_) { lk[pos] = k; lkey[pos] = key; }
    }
  }
  __syncthreads();                                             // B7
  const int L = min((int)scal[3], LCAP_);
  for (int i = tid; i < L; i += 256) {
    unsigned int key = lkey[i];
    int k = lk[i];
    int cnt = run2;
    for (int m = 0; m < L; ++m)
      cnt += (int)((lkey[m] > key) || (lkey[m] == key && lk[m] < k));
    if (cnt < KS_) {
      unsigned int slot = atomicAdd(&scal[2], 1u);
      int aa = k / 27, bb = k - aa * 27;
      int ni = min(max(qi + aa - 13, 0), H_ - 1);
      int nj = min(max(qj + bb - 13, 0), W_ - 1);
      float wv = __expf(SCALE_ * (dist[k] - dmax));
      sel_n[outb + slot] = (ni << 7) | nj;
      sel_w[outb + slot] = wv;
      lsum += wv;
    }
  }
#pragma unroll
  for (int off = 32; off > 0; off >>= 1) lsum += __shfl_down(lsum, off, 64);
  __syncthreads();                                             // B8
  if (lane == 0) redf[wid] = lsum;
  __syncthreads();                                             // B9
  if (tid == 0) wsum_out[t * NQ_ + q] = (redf[0] + redf[1]) + (redf[2] + redf[3]);
}

// ---------------- weighted aggregation + fold (direct L2 gather) ------------
__global__ __launch_bounds__(256) void agg_kernel(
    const float4* __restrict__ v2cs, const int* __restrict__ sel_n,
    const float* __restrict__ sel_w, const float* __restrict__ wsum,
    float* __restrict__ Y) {
  __shared__ int s_ni[KS_], s_nj[KS_];
  __shared__ float s_w[KS_];
  const int tid = threadIdx.x;
  const int q = blockIdx.x, t = blockIdx.y;
  const int qi = (q >> 5) * S0_, qj = (q & 31) * S0_;
  const size_t base = ((size_t)t * NQ_ + q) * KS_;
  if (tid < KS_) {
    int n = sel_n[base + tid];
    s_ni[tid] = n >> 7;
    s_nj[tid] = n & 127;
    s_w[tid] = sel_w[base + tid] / wsum[t * NQ_ + q];
  }
  __syncthreads();
  const int cc = tid >> 6, lane = tid & 63;
  if (lane >= 49) return;
  const int r = lane / 7, s = lane - r * 7;
  const float4* src = v2cs + ((size_t)cc * T_ + t) * HW_;
  float4 acc = make_float4(0.f, 0.f, 0.f, 0.f);
#pragma unroll 4
  for (int k = 0; k < KS_; ++k) {
    int ri = min(s_ni[k] + r, H_ - 1);
    int ci = min(s_nj[k] + s, W_ - 1);
    float4 v = src[ri * W_ + ci];
    float w = s_w[k];
    acc.x = fmaf(w, v.x, acc.x);
    acc.y = fmaf(w, v.y, acc.y);
    acc.z = fmaf(w, v.z, acc.z);
    acc.w = fmaf(w, v.w, acc.w);
  }
  const int oi = min(qi + r, H_ - 1), oj = min(qj + s, W_ - 1);
  float* yb = Y + (((size_t)t * CI_ + cc * 4) * H_ + oi) * W_ + oj;
  atomicAdd(yb, acc.x);
  atomicAdd(yb + HW_, acc.y);
  atomicAdd(yb + 2 * HW_, acc.z);
  atomicAdd(yb + 3 * HW_, acc.w);
}

// ---------------- normalize by analytic fold counts -------------------------
__device__ __forceinline__ int cov_axis(int x) {
  int c = 0;
#pragma unroll
  for (int r = 0; r < 7; ++r) {
    if (x < H_ - 1) {
      int qb = x - r;
      c += (qb >= 0 && (qb & 3) == 0) ? 1 : 0;
    } else {
      c += (r >= 3) ? 1 : 0;
    }
  }
  return c;
}

__global__ void norm_kernel(float* __restrict__ Y) {
  int idx = blockIdx.x * blockDim.x + threadIdx.x;
  if (idx >= T_ * CI_ * HW_) return;
  int p = idx & (HW_ - 1);
  float z = (float)(cov_axis(p >> 7) * cov_axis(p & 127));
  Y[idx] /= z;
}

extern "C" void kernel_launch(void* const* d_in, const int* in_sizes, int n_in,
                              void* d_out, int out_size, void* d_ws, size_t ws_size,
                              hipStream_t stream) {
  const float* vid     = (const float*)d_in[0];
  const float* g_w     = (const float*)d_in[1];
  const float* g_b     = (const float*)d_in[2];
  const float* theta_w = (const float*)d_in[3];
  const float* theta_b = (const float*)d_in[4];
  float* Y = (float*)d_out;

  // workspace (floats): v1cs | v2cs | distG | sel_n | sel_w | wsum  (~24 MB)
  float* v1cs  = (float*)d_ws;
  float* v2cs  = v1cs + (size_t)4 * T_ * HW_ * 4;              // 1048576
  float* distG = v2cs + (size_t)4 * T_ * HW_ * 4;              // 1048576
  int*   sel_n = (int*)(distG + (size_t)T_ * NQ_ * NC_);       // 2985984
  float* sel_w = (float*)(sel_n + (size_t)T_ * NQ_ * KS_);     // 409600
  float* wsumv = sel_w + (size_t)T_ * NQ_ * KS_;               // 409600

  hipMemsetAsync(Y, 0, (size_t)out_size * sizeof(float), stream);

  conv3x3_kernel<<<dim3(64, 4, T_), 128, 0, stream>>>(vid, g_w, g_b, (float4*)v1cs);
  conv1x1_kernel<<<dim3(HW_ / 256, T_, 4), 256, 0, stream>>>(vid, theta_w, theta_b, (float4*)v2cs);
  dist_kernel<<<dim3(64, T_), 1024, 0, stream>>>((const float4*)v1cs, distG);
  select_kernel<<<dim3(NQ_, T_), 256, 0, stream>>>(distG, sel_n, sel_w, wsumv);
  agg_kernel<<<dim3(NQ_, T_), 256, 0, stream>>>((const float4*)v2cs, sel_n, sel_w, wsumv, Y);
  norm_kernel<<<(T_ * CI_ * HW_ + 255) / 256, 256, 0, stream>>>(Y);
}

// Round 13
// 338.640 us; speedup vs baseline: 1.0310x; 1.0097x over previous
//
#include <hip/hip_runtime.h>
#include <hip/hip_bf16.h>

#define T_ 4
#define C_ 64
#define H_ 128
#define W_ 128
#define CI_ 16
#define PS_ 7
#define NC_ 729       // 27*27 candidates per query
#define S0_ 4
#define KS_ 100
#define NQ_ 1024      // 32*32 queries per frame
#define SCALE_ 10.0f
#define HW_ (H_*W_)
#define RW_ 45        // 4x4-tile region dim (float4); 45%8=5 -> bank rotation
#define LCAP_ 768
#define CB_ 8         // conv3x3 channel batch (24 dwordx4 in flight)

typedef float v2f __attribute__((ext_vector_type(2)));
#if __has_builtin(__builtin_elementwise_fma)
#define VFMA(a, b, c) __builtin_elementwise_fma((a), (b), (c))
#else
#define VFMA(a, b, c) ((a) * (b) + (c))
#endif

// ---------------- conv 3x3, 64->16, 2px/thread, 8-channel load batches ------
// Grid (64, 4, T): 16x16 tile, 128 threads, co-group g of 4 = output chunk g.
// __launch_bounds__(128,1): min-1-wave/EU unlocks VGPR budget so the 24
// dwordx4 batch (96 VGPRs) stays register-resident and in flight (MLP).
__device__ __forceinline__ float4 ldrow3(const float* p, int row, int c0,
                                         bool rok, bool fast) {
  float4 r = make_float4(0.f, 0.f, 0.f, 0.f);
  if (!rok) return r;
  const float* rp = p + row * W_;
  if (fast) {
    r = *(const float4*)(rp + c0);
  } else {
    if (c0 >= 0) r.x = rp[c0];
    if (c0 + 1 >= 0 && c0 + 1 < W_) r.y = rp[c0 + 1];
    if (c0 + 2 < W_) r.z = rp[c0 + 2];
    if (c0 + 3 < W_) r.w = rp[c0 + 3];
  }
  return r;
}

__global__ __launch_bounds__(128, 1) void conv3x3_kernel(
    const float* __restrict__ vid, const float* __restrict__ gw,
    const float* __restrict__ gb, float4* __restrict__ v1cs) {
  __shared__ float wls[C_ * 9 * 4];   // [c][k][co]
  const int tid = threadIdx.x;
  const int g = blockIdx.y, t = blockIdx.z;
  for (int m = tid; m < C_ * 9 * 4; m += 128) {
    int co = m & 3, ck = m >> 2;
    wls[m] = gw[((size_t)(g * 4 + co) * C_) * 9 + ck];
  }
  __syncthreads();
  const int ti0 = (blockIdx.x >> 3) * 16, tj0 = (blockIdx.x & 7) * 16;
  const int u = tid >> 3, v = tid & 7;   // 16 rows x 8 col-pairs
  const int i = ti0 + u, j0 = tj0 + 2 * v;
  const int c0 = j0 - 1;
  const bool fast = (c0 >= 0) && (c0 + 3 < W_);
  const bool rok0 = (i - 1 >= 0), rok2 = (i + 1 < H_);

  float accA[4], accB[4];
#pragma unroll
  for (int co = 0; co < 4; ++co) { accA[co] = gb[g * 4 + co]; accB[co] = gb[g * 4 + co]; }

  const float* vb = vid + ((size_t)t * C_) * HW_;
#pragma unroll 1
  for (int cb = 0; cb < C_; cb += CB_) {
    float4 r[CB_][3];
#pragma unroll
    for (int c = 0; c < CB_; ++c) {       // 24 independent loads issued first
      const float* p = vb + (size_t)(cb + c) * HW_;
      r[c][0] = ldrow3(p, i - 1, c0, rok0, fast);
      r[c][1] = ldrow3(p, i,     c0, true, fast);
      r[c][2] = ldrow3(p, i + 1, c0, rok2, fast);
    }
#pragma unroll
    for (int c = 0; c < CB_; ++c) {
      const float* wc = &wls[(cb + c) * 36];   // [k][co]
      float e0[4] = {r[c][0].x, r[c][0].y, r[c][0].z, r[c][0].w};
      float e1[4] = {r[c][1].x, r[c][1].y, r[c][1].z, r[c][1].w};
      float e2[4] = {r[c][2].x, r[c][2].y, r[c][2].z, r[c][2].w};
#pragma unroll
      for (int kj = 0; kj < 3; ++kj) {
#pragma unroll
        for (int co = 0; co < 4; ++co) {
          accA[co] = fmaf(wc[(0 * 3 + kj) * 4 + co], e0[kj],     accA[co]);
          accB[co] = fmaf(wc[(0 * 3 + kj) * 4 + co], e0[kj + 1], accB[co]);
          accA[co] = fmaf(wc[(1 * 3 + kj) * 4 + co], e1[kj],     accA[co]);
          accB[co] = fmaf(wc[(1 * 3 + kj) * 4 + co], e1[kj + 1], accB[co]);
          accA[co] = fmaf(wc[(2 * 3 + kj) * 4 + co], e2[kj],     accA[co]);
          accB[co] = fmaf(wc[(2 * 3 + kj) * 4 + co], e2[kj + 1], accB[co]);
        }
      }
    }
  }
  const size_t o = ((size_t)g * T_ + t) * HW_ + i * W_ + j0;
  v1cs[o]     = make_float4(accA[0], accA[1], accA[2], accA[3]);
  v1cs[o + 1] = make_float4(accB[0], accB[1], accB[2], accB[3]);
}

// ---------------- conv 1x1, 64->16, chunk-major float4 output ----------------
__global__ __launch_bounds__(256, 1) void conv1x1_kernel(
    const float* __restrict__ vid, const float* __restrict__ tw,
    const float* __restrict__ tb, float4* __restrict__ v2cs) {
  __shared__ float w[C_ * 4];
  const int t = blockIdx.y, cc = blockIdx.z;
  for (int m = threadIdx.x; m < C_ * 4; m += 256) {
    int o = m & 3, c = m >> 2;
    w[m] = tw[(cc * 4 + o) * C_ + c];
  }
  __syncthreads();
  const int pix = blockIdx.x * 256 + threadIdx.x;
  float acc[4];
#pragma unroll
  for (int o = 0; o < 4; ++o) acc[o] = tb[cc * 4 + o];
  const float* vb = vid + ((size_t)t * C_) * HW_ + pix;
#pragma unroll 1
  for (int c0 = 0; c0 < C_; c0 += 16) {
    float x[16];
#pragma unroll
    for (int uu = 0; uu < 16; ++uu) x[uu] = vb[(size_t)(c0 + uu) * HW_];
#pragma unroll
    for (int uu = 0; uu < 16; ++uu)
#pragma unroll
      for (int o = 0; o < 4; ++o)
        acc[o] = fmaf(w[(c0 + uu) * 4 + o], x[uu], acc[o]);
  }
  v2cs[((size_t)cc * T_ + t) * HW_ + pix] = make_float4(acc[0], acc[1], acc[2], acc[3]);
}

// ---------------- dists: 4x4-query tile, packed v_pk_fma_f32 accumulators ---
__global__ __launch_bounds__(1024) void dist_kernel(
    const float4* __restrict__ v1cs, float* __restrict__ distG) {
  __shared__ float4 Rs[RW_ * RW_];
  const int tid = threadIdx.x;
  const int t = blockIdx.y;
  const int qi0 = (blockIdx.x >> 3) * 16, qj0 = (blockIdx.x & 7) * 16;
  const int w = tid >> 6, lane = tid & 63;
  const int di = (w >> 2) * 4, dj = (w & 3) * 4;
  const int qi = qi0 + di, qj = qj0 + dj;
  const int a_lo = max(13 - qi, 0), b_lo = max(13 - qj, 0);
  const int ai = lane >> 1, bg = lane & 1;
  const bool active = ai < 27;
  const int a = min(a_lo + ai, 26);
  const int bs = bg ? 13 : b_lo;

  v2f acc2[14];
#pragma unroll
  for (int j = 0; j < 14; ++j) acc2[j] = (v2f){0.f, 0.f};

#pragma unroll 1
  for (int cc = 0; cc < 4; ++cc) {
    __syncthreads();
    const float4* src = v1cs + ((size_t)cc * T_ + t) * HW_;
    for (int p = tid; p < RW_ * RW_; p += 1024) {
      int uu = p / RW_, vv = p - uu * RW_;
      int row = min(max(qi0 - 13 + uu, 0), H_ - 1);
      int col = min(max(qj0 - 13 + vv, 0), W_ - 1);
      Rs[p] = src[row * W_ + col];
    }
    __syncthreads();
    if (active) {
#pragma unroll 1
      for (int r = 0; r < 7; ++r) {
        v2f qlo[7], qhi[7];
        const float4* qrow = &Rs[(di + 13 + r) * RW_ + dj + 13];
#pragma unroll
        for (int s = 0; s < 7; ++s) {
          float4 qq = qrow[s];
          qlo[s] = (v2f){qq.x, qq.y};
          qhi[s] = (v2f){qq.z, qq.w};
        }
        const float4* crow = &Rs[(di + a + r) * RW_ + dj + bs];
#pragma unroll
        for (int y = 0; y < 20; ++y) {
          float4 vv = crow[y];
          v2f vlo = (v2f){vv.x, vv.y}, vhi = (v2f){vv.z, vv.w};
          const int s_lo = (y > 13) ? (y - 13) : 0;
          const int s_hi = (y < 6) ? y : 6;
#pragma unroll
          for (int s = s_lo; s <= s_hi; ++s) {
            int j = y - s;
            acc2[j] = VFMA(qlo[s], vlo, acc2[j]);
            acc2[j] = VFMA(qhi[s], vhi, acc2[j]);
          }
        }
      }
    }
  }
  if (active) {
    const int q = ((qi >> 2) << 5) + (qj >> 2);
    float* out = distG + ((size_t)t * NQ_ + q) * NC_ + a * 27 + bs;
#pragma unroll
    for (int j = 0; j < 14; ++j) out[j] = acc2[j].x + acc2[j].y;
  }
}

// ---------------- select: 2-level radix top-100, wave-primitive scans -------
__global__ __launch_bounds__(256) void select_kernel(
    const float* __restrict__ distG, int* __restrict__ sel_n,
    float* __restrict__ sel_w, float* __restrict__ wsum_out) {
  __shared__ float dist[NC_];
  __shared__ unsigned int ukey[NC_];
  __shared__ float redf[4];
  __shared__ unsigned int hist[256];
  __shared__ int lk[LCAP_];
  __shared__ unsigned int lkey[LCAP_];
  __shared__ unsigned int scal[6];   // 0=beta 1=run 2=cursor 3=listlen 4=beta2 5=run2

  const int tid = threadIdx.x;
  const int lane = tid & 63, wid = tid >> 6;
  const int q = blockIdx.x, t = blockIdx.y;
  const int qi = (q >> 5) * S0_, qj = (q & 31) * S0_;
  const int a_lo = max(13 - qi, 0), b_lo = max(13 - qj, 0);
  const size_t base = ((size_t)t * NQ_ + q) * NC_;

  for (int h = tid; h < 256; h += 256) hist[h] = 0;
  if (tid == 0) { scal[2] = 0; scal[3] = 0; }
  float lmax = -INFINITY;
  for (int k = tid; k < NC_; k += 256) {
    int aa = k / 27, bb = k - aa * 27;
    int kk = max(aa, a_lo) * 27 + max(bb, b_lo);
    float d = distG[base + kk];
    dist[k] = d;
    unsigned int u = __float_as_uint(d);
    ukey[k] = u ^ (((unsigned int)((int)u >> 31)) | 0x80000000u);
    lmax = fmaxf(lmax, d);
  }
#pragma unroll
  for (int off = 32; off > 0; off >>= 1)
    lmax = fmaxf(lmax, __shfl_down(lmax, off, 64));
  if (lane == 0) redf[wid] = lmax;
  __syncthreads();                                             // B1
  const float dmax = fmaxf(fmaxf(redf[0], redf[1]), fmaxf(redf[2], redf[3]));
  for (int k = tid; k < NC_; k += 256) atomicAdd(&hist[ukey[k] >> 24], 1u);
  __syncthreads();                                             // B2
  if (wid == 0) {
    int s4 = (int)(hist[lane * 4] + hist[lane * 4 + 1] + hist[lane * 4 + 2] + hist[lane * 4 + 3]);
    int s = s4;
#pragma unroll
    for (int off = 1; off < 64; off <<= 1) {
      int o = __shfl_down(s, off, 64);
      if (lane + off < 64) s += o;
    }
    int above = s - s4;
    if (above < KS_ && s >= KS_) {
      int run = above;
#pragma unroll
      for (int bb = 3; bb >= 0; --bb) {
        int h = (int)hist[lane * 4 + bb];
        if (run + h >= KS_) { scal[0] = (unsigned int)(lane * 4 + bb); scal[1] = (unsigned int)run; break; }
        run += h;
      }
    }
  }
  __syncthreads();                                             // B3
  const unsigned int beta = scal[0];
  const int run = (int)scal[1];
  for (int h = tid; h < 256; h += 256) hist[h] = 0;
  __syncthreads();                                             // B4
  for (int k = tid; k < NC_; k += 256)
    if ((ukey[k] >> 24) == beta) atomicAdd(&hist[(ukey[k] >> 16) & 0xFFu], 1u);
  __syncthreads();                                             // B5
  if (wid == 0) {
    int s4 = (int)(hist[lane * 4] + hist[lane * 4 + 1] + hist[lane * 4 + 2] + hist[lane * 4 + 3]);
    int s = s4;
#pragma unroll
    for (int off = 1; off < 64; off <<= 1) {
      int o = __shfl_down(s, off, 64);
      if (lane + off < 64) s += o;
    }
    int above = run + s - s4;
    if (above < KS_ && run + s >= KS_) {
      int r2 = above;
#pragma unroll
      for (int bb = 3; bb >= 0; --bb) {
        int h = (int)hist[lane * 4 + bb];
        if (r2 + h >= KS_) { scal[4] = (unsigned int)(lane * 4 + bb); scal[5] = (unsigned int)r2; break; }
        r2 += h;
      }
    }
  }
  __syncthreads();                                             // B6
  const unsigned int beta2 = scal[4];
  const int run2 = (int)scal[5];
  const size_t outb = ((size_t)t * NQ_ + q) * KS_;
  float lsum = 0.f;
  for (int k = tid; k < NC_; k += 256) {
    unsigned int key = ukey[k];
    unsigned int bin = key >> 24;
    bool sel = false, bdry = false;
    if (bin > beta) sel = true;
    else if (bin == beta) {
      unsigned int b2 = (key >> 16) & 0xFFu;
      if (b2 > beta2) sel = true;
      else if (b2 == beta2) bdry = true;
    }
    if (sel) {
      unsigned int slot = atomicAdd(&scal[2], 1u);
      int aa = k / 27, bb = k - aa * 27;
      int ni = min(max(qi + aa - 13, 0), H_ - 1);
      int nj = min(max(qj + bb - 13, 0), W_ - 1);
      float wv = __expf(SCALE_ * (dist[k] - dmax));
      sel_n[outb + slot] = (ni << 7) | nj;
      sel_w[outb + slot] = wv;
      lsum += wv;
    } else if (bdry) {
      unsigned int pos = atomicAdd(&scal[3], 1u);
      if (pos < LCAP_) { lk[pos] = k; lkey[pos] = key; }
    }
  }
  __syncthreads();                                             // B7
  const int L = min((int)scal[3], LCAP_);
  for (int i = tid; i < L; i += 256) {
    unsigned int key = lkey[i];
    int k = lk[i];
    int cnt = run2;
    for (int m = 0; m < L; ++m)
      cnt += (int)((lkey[m] > key) || (lkey[m] == key && lk[m] < k));
    if (cnt < KS_) {
      unsigned int slot = atomicAdd(&scal[2], 1u);
      int aa = k / 27, bb = k - aa * 27;
      int ni = min(max(qi + aa - 13, 0), H_ - 1);
      int nj = min(max(qj + bb - 13, 0), W_ - 1);
      float wv = __expf(SCALE_ * (dist[k] - dmax));
      sel_n[outb + slot] = (ni << 7) | nj;
      sel_w[outb + slot] = wv;
      lsum += wv;
    }
  }
#pragma unroll
  for (int off = 32; off > 0; off >>= 1) lsum += __shfl_down(lsum, off, 64);
  __syncthreads();                                             // B8
  if (lane == 0) redf[wid] = lsum;
  __syncthreads();                                             // B9
  if (tid == 0) wsum_out[t * NQ_ + q] = (redf[0] + redf[1]) + (redf[2] + redf[3]);
}

// ---------------- weighted aggregation + fold (direct L2 gather) ------------
__global__ __launch_bounds__(256) void agg_kernel(
    const float4* __restrict__ v2cs, const int* __restrict__ sel_n,
    const float* __restrict__ sel_w, const float* __restrict__ wsum,
    float* __restrict__ Y) {
  __shared__ int s_ni[KS_], s_nj[KS_];
  __shared__ float s_w[KS_];
  const int tid = threadIdx.x;
  const int q = blockIdx.x, t = blockIdx.y;
  const int qi = (q >> 5) * S0_, qj = (q & 31) * S0_;
  const size_t base = ((size_t)t * NQ_ + q) * KS_;
  if (tid < KS_) {
    int n = sel_n[base + tid];
    s_ni[tid] = n >> 7;
    s_nj[tid] = n & 127;
    s_w[tid] = sel_w[base + tid] / wsum[t * NQ_ + q];
  }
  __syncthreads();
  const int cc = tid >> 6, lane = tid & 63;
  if (lane >= 49) return;
  const int r = lane / 7, s = lane - r * 7;
  const float4* src = v2cs + ((size_t)cc * T_ + t) * HW_;
  float4 acc = make_float4(0.f, 0.f, 0.f, 0.f);
#pragma unroll 4
  for (int k = 0; k < KS_; ++k) {
    int ri = min(s_ni[k] + r, H_ - 1);
    int ci = min(s_nj[k] + s, W_ - 1);
    float4 v = src[ri * W_ + ci];
    float w = s_w[k];
    acc.x = fmaf(w, v.x, acc.x);
    acc.y = fmaf(w, v.y, acc.y);
    acc.z = fmaf(w, v.z, acc.z);
    acc.w = fmaf(w, v.w, acc.w);
  }
  const int oi = min(qi + r, H_ - 1), oj = min(qj + s, W_ - 1);
  float* yb = Y + (((size_t)t * CI_ + cc * 4) * H_ + oi) * W_ + oj;
  atomicAdd(yb, acc.x);
  atomicAdd(yb + HW_, acc.y);
  atomicAdd(yb + 2 * HW_, acc.z);
  atomicAdd(yb + 3 * HW_, acc.w);
}

// ---------------- normalize by analytic fold counts -------------------------
__device__ __forceinline__ int cov_axis(int x) {
  int c = 0;
#pragma unroll
  for (int r = 0; r < 7; ++r) {
    if (x < H_ - 1) {
      int qb = x - r;
      c += (qb >= 0 && (qb & 3) == 0) ? 1 : 0;
    } else {
      c += (r >= 3) ? 1 : 0;
    }
  }
  return c;
}

__global__ void norm_kernel(float* __restrict__ Y) {
  int idx = blockIdx.x * blockDim.x + threadIdx.x;
  if (idx >= T_ * CI_ * HW_) return;
  int p = idx & (HW_ - 1);
  float z = (float)(cov_axis(p >> 7) * cov_axis(p & 127));
  Y[idx] /= z;
}

extern "C" void kernel_launch(void* const* d_in, const int* in_sizes, int n_in,
                              void* d_out, int out_size, void* d_ws, size_t ws_size,
                              hipStream_t stream) {
  const float* vid     = (const float*)d_in[0];
  const float* g_w     = (const float*)d_in[1];
  const float* g_b     = (const float*)d_in[2];
  const float* theta_w = (const float*)d_in[3];
  const float* theta_b = (const float*)d_in[4];
  float* Y = (float*)d_out;

  // workspace (floats): v1cs | v2cs | distG | sel_n | sel_w | wsum  (~24 MB)
  float* v1cs  = (float*)d_ws;
  float* v2cs  = v1cs + (size_t)4 * T_ * HW_ * 4;              // 1048576
  float* distG = v2cs + (size_t)4 * T_ * HW_ * 4;              // 1048576
  int*   sel_n = (int*)(distG + (size_t)T_ * NQ_ * NC_);       // 2985984
  float* sel_w = (float*)(sel_n + (size_t)T_ * NQ_ * KS_);     // 409600
  float* wsumv = sel_w + (size_t)T_ * NQ_ * KS_;               // 409600

  hipMemsetAsync(Y, 0, (size_t)out_size * sizeof(float), stream);

  conv3x3_kernel<<<dim3(64, 4, T_), 128, 0, stream>>>(vid, g_w, g_b, (float4*)v1cs);
  conv1x1_kernel<<<dim3(HW_ / 256, T_, 4), 256, 0, stream>>>(vid, theta_w, theta_b, (float4*)v2cs);
  dist_kernel<<<dim3(64, T_), 1024, 0, stream>>>((const float4*)v1cs, distG);
  select_kernel<<<dim3(NQ_, T_), 256, 0, stream>>>(distG, sel_n, sel_w, wsumv);
  agg_kernel<<<dim3(NQ_, T_), 256, 0, stream>>>((const float4*)v2cs, sel_n, sel_w, wsumv, Y);
  norm_kernel<<<(T_ * CI_ * HW_ + 255) / 256, 256, 0, stream>>>(Y);
}

// Round 14
// 288.570 us; speedup vs baseline: 1.2099x; 1.1735x over previous
//
#include <hip/hip_runtime.h>
#include <hip/hip_bf16.h>

#define T_ 4
#define C_ 64
#define H_ 128
#define W_ 128
#define CI_ 16
#define PS_ 7
#define NC_ 729       // 27*27 candidates per query
#define S0_ 4
#define KS_ 100
#define NQ_ 1024      // 32*32 queries per frame
#define SCALE_ 10.0f
#define HW_ (H_*W_)
#define RW_ 45        // 4x4-tile region dim (float4); 45%8=5 -> bank rotation
#define LCAP_ 768
#define CB_ 8         // conv3x3 channel batch (24 dwordx4 in flight)

typedef float v2f __attribute__((ext_vector_type(2)));
#if __has_builtin(__builtin_elementwise_fma)
#define VFMA(a, b, c) __builtin_elementwise_fma((a), (b), (c))
#else
#define VFMA(a, b, c) ((a) * (b) + (c))
#endif

// ---------------- conv 3x3, 64->16, BRANCH-FREE batched loads ---------------
// Grid (64, 4, T): 16x16 tile, 128 threads, 2px/thread, co-group g of 4.
// All loads unconditional at clamped addresses (hoistable -> 24 in flight);
// borders repaired in registers: col = 1-elem shift+zero, row = 0/1 mask.
// Produces bit-identical v1 vs predicated version.
__device__ __forceinline__ float4 colfix(float4 r, bool loB, bool hiB) {
  // loB (c0=-1, loaded at 0):   want [0,  r.x, r.y, r.z]
  // hiB (c0=125, loaded at 124): want [r.y, r.z, r.w, 0 ]
  float4 o;
  o.x = loB ? 0.f : (hiB ? r.y : r.x);
  o.y = loB ? r.x : (hiB ? r.z : r.y);
  o.z = loB ? r.y : (hiB ? r.w : r.z);
  o.w = loB ? r.z : (hiB ? 0.f : r.w);
  return o;
}

__global__ __launch_bounds__(128, 1) void conv3x3_kernel(
    const float* __restrict__ vid, const float* __restrict__ gw,
    const float* __restrict__ gb, float4* __restrict__ v1cs) {
  __shared__ float wls[C_ * 9 * 4];   // [c][k][co]
  const int tid = threadIdx.x;
  const int g = blockIdx.y, t = blockIdx.z;
  for (int m = tid; m < C_ * 9 * 4; m += 128) {
    int co = m & 3, ck = m >> 2;
    wls[m] = gw[((size_t)(g * 4 + co) * C_) * 9 + ck];
  }
  __syncthreads();
  const int ti0 = (blockIdx.x >> 3) * 16, tj0 = (blockIdx.x & 7) * 16;
  const int u = tid >> 3, v = tid & 7;   // 16 rows x 8 col-pairs
  const int i = ti0 + u, j0 = tj0 + 2 * v;
  const int c0 = j0 - 1;
  const int c0c = min(max(c0, 0), W_ - 4);
  const bool loB = (c0 < 0), hiB = (c0 > W_ - 4);
  const int rm1 = max(i - 1, 0), rp1 = min(i + 1, H_ - 1);
  const float mk0 = (i > 0) ? 1.f : 0.f;
  const float mk2 = (i < H_ - 1) ? 1.f : 0.f;
  const int o0 = rm1 * W_ + c0c, o1 = i * W_ + c0c, o2 = rp1 * W_ + c0c;

  float accA[4], accB[4];
#pragma unroll
  for (int co = 0; co < 4; ++co) { accA[co] = gb[g * 4 + co]; accB[co] = gb[g * 4 + co]; }

  const float* vb = vid + ((size_t)t * C_) * HW_;
#pragma unroll 1
  for (int cb = 0; cb < C_; cb += CB_) {
    float4 r[CB_][3];
#pragma unroll
    for (int c = 0; c < CB_; ++c) {       // 24 UNCONDITIONAL loads -> in flight
      const float* p = vb + (size_t)(cb + c) * HW_;
      r[c][0] = *(const float4*)(p + o0);
      r[c][1] = *(const float4*)(p + o1);
      r[c][2] = *(const float4*)(p + o2);
    }
#pragma unroll
    for (int c = 0; c < CB_; ++c) {
      float4 f0 = colfix(r[c][0], loB, hiB);
      float4 f1 = colfix(r[c][1], loB, hiB);
      float4 f2 = colfix(r[c][2], loB, hiB);
      f0.x *= mk0; f0.y *= mk0; f0.z *= mk0; f0.w *= mk0;
      f2.x *= mk2; f2.y *= mk2; f2.z *= mk2; f2.w *= mk2;
      const float* wc = &wls[c ? (cb + c) * 36 : cb * 36];
      float e0[4] = {f0.x, f0.y, f0.z, f0.w};
      float e1[4] = {f1.x, f1.y, f1.z, f1.w};
      float e2[4] = {f2.x, f2.y, f2.z, f2.w};
#pragma unroll
      for (int kj = 0; kj < 3; ++kj) {
#pragma unroll
        for (int co = 0; co < 4; ++co) {
          accA[co] = fmaf(wc[(0 * 3 + kj) * 4 + co], e0[kj],     accA[co]);
          accB[co] = fmaf(wc[(0 * 3 + kj) * 4 + co], e0[kj + 1], accB[co]);
          accA[co] = fmaf(wc[(1 * 3 + kj) * 4 + co], e1[kj],     accA[co]);
          accB[co] = fmaf(wc[(1 * 3 + kj) * 4 + co], e1[kj + 1], accB[co]);
          accA[co] = fmaf(wc[(2 * 3 + kj) * 4 + co], e2[kj],     accA[co]);
          accB[co] = fmaf(wc[(2 * 3 + kj) * 4 + co], e2[kj + 1], accB[co]);
        }
      }
    }
  }
  const size_t o = ((size_t)g * T_ + t) * HW_ + i * W_ + j0;
  v1cs[o]     = make_float4(accA[0], accA[1], accA[2], accA[3]);
  v1cs[o + 1] = make_float4(accB[0], accB[1], accB[2], accB[3]);
}

// ---------------- conv 1x1, 64->16, chunk-major float4 output ----------------
__global__ __launch_bounds__(256, 1) void conv1x1_kernel(
    const float* __restrict__ vid, const float* __restrict__ tw,
    const float* __restrict__ tb, float4* __restrict__ v2cs) {
  __shared__ float w[C_ * 4];
  const int t = blockIdx.y, cc = blockIdx.z;
  for (int m = threadIdx.x; m < C_ * 4; m += 256) {
    int o = m & 3, c = m >> 2;
    w[m] = tw[(cc * 4 + o) * C_ + c];
  }
  __syncthreads();
  const int pix = blockIdx.x * 256 + threadIdx.x;
  float acc[4];
#pragma unroll
  for (int o = 0; o < 4; ++o) acc[o] = tb[cc * 4 + o];
  const float* vb = vid + ((size_t)t * C_) * HW_ + pix;
#pragma unroll 1
  for (int c0 = 0; c0 < C_; c0 += 16) {
    float x[16];
#pragma unroll
    for (int uu = 0; uu < 16; ++uu) x[uu] = vb[(size_t)(c0 + uu) * HW_];
#pragma unroll
    for (int uu = 0; uu < 16; ++uu)
#pragma unroll
      for (int o = 0; o < 4; ++o)
        acc[o] = fmaf(w[(c0 + uu) * 4 + o], x[uu], acc[o]);
  }
  v2cs[((size_t)cc * T_ + t) * HW_ + pix] = make_float4(acc[0], acc[1], acc[2], acc[3]);
}

// ---------------- dists: 4x4-query tile, packed v_pk_fma_f32 accumulators ---
__global__ __launch_bounds__(1024) void dist_kernel(
    const float4* __restrict__ v1cs, float* __restrict__ distG) {
  __shared__ float4 Rs[RW_ * RW_];
  const int tid = threadIdx.x;
  const int t = blockIdx.y;
  const int qi0 = (blockIdx.x >> 3) * 16, qj0 = (blockIdx.x & 7) * 16;
  const int w = tid >> 6, lane = tid & 63;
  const int di = (w >> 2) * 4, dj = (w & 3) * 4;
  const int qi = qi0 + di, qj = qj0 + dj;
  const int a_lo = max(13 - qi, 0), b_lo = max(13 - qj, 0);
  const int ai = lane >> 1, bg = lane & 1;
  const bool active = ai < 27;
  const int a = min(a_lo + ai, 26);
  const int bs = bg ? 13 : b_lo;

  v2f acc2[14];
#pragma unroll
  for (int j = 0; j < 14; ++j) acc2[j] = (v2f){0.f, 0.f};

#pragma unroll 1
  for (int cc = 0; cc < 4; ++cc) {
    __syncthreads();
    const float4* src = v1cs + ((size_t)cc * T_ + t) * HW_;
    for (int p = tid; p < RW_ * RW_; p += 1024) {
      int uu = p / RW_, vv = p - uu * RW_;
      int row = min(max(qi0 - 13 + uu, 0), H_ - 1);
      int col = min(max(qj0 - 13 + vv, 0), W_ - 1);
      Rs[p] = src[row * W_ + col];
    }
    __syncthreads();
    if (active) {
#pragma unroll 1
      for (int r = 0; r < 7; ++r) {
        v2f qlo[7], qhi[7];
        const float4* qrow = &Rs[(di + 13 + r) * RW_ + dj + 13];
#pragma unroll
        for (int s = 0; s < 7; ++s) {
          float4 qq = qrow[s];
          qlo[s] = (v2f){qq.x, qq.y};
          qhi[s] = (v2f){qq.z, qq.w};
        }
        const float4* crow = &Rs[(di + a + r) * RW_ + dj + bs];
#pragma unroll
        for (int y = 0; y < 20; ++y) {
          float4 vv = crow[y];
          v2f vlo = (v2f){vv.x, vv.y}, vhi = (v2f){vv.z, vv.w};
          const int s_lo = (y > 13) ? (y - 13) : 0;
          const int s_hi = (y < 6) ? y : 6;
#pragma unroll
          for (int s = s_lo; s <= s_hi; ++s) {
            int j = y - s;
            acc2[j] = VFMA(qlo[s], vlo, acc2[j]);
            acc2[j] = VFMA(qhi[s], vhi, acc2[j]);
          }
        }
      }
    }
  }
  if (active) {
    const int q = ((qi >> 2) << 5) + (qj >> 2);
    float* out = distG + ((size_t)t * NQ_ + q) * NC_ + a * 27 + bs;
#pragma unroll
    for (int j = 0; j < 14; ++j) out[j] = acc2[j].x + acc2[j].y;
  }
}

// ---------------- select: 2-level radix top-100, wave-primitive scans -------
__global__ __launch_bounds__(256) void select_kernel(
    const float* __restrict__ distG, int* __restrict__ sel_n,
    float* __restrict__ sel_w, float* __restrict__ wsum_out) {
  __shared__ float dist[NC_];
  __shared__ unsigned int ukey[NC_];
  __shared__ float redf[4];
  __shared__ unsigned int hist[256];
  __shared__ int lk[LCAP_];
  __shared__ unsigned int lkey[LCAP_];
  __shared__ unsigned int scal[6];   // 0=beta 1=run 2=cursor 3=listlen 4=beta2 5=run2

  const int tid = threadIdx.x;
  const int lane = tid & 63, wid = tid >> 6;
  const int q = blockIdx.x, t = blockIdx.y;
  const int qi = (q >> 5) * S0_, qj = (q & 31) * S0_;
  const int a_lo = max(13 - qi, 0), b_lo = max(13 - qj, 0);
  const size_t base = ((size_t)t * NQ_ + q) * NC_;

  for (int h = tid; h < 256; h += 256) hist[h] = 0;
  if (tid == 0) { scal[2] = 0; scal[3] = 0; }
  float lmax = -INFINITY;
  for (int k = tid; k < NC_; k += 256) {
    int aa = k / 27, bb = k - aa * 27;
    int kk = max(aa, a_lo) * 27 + max(bb, b_lo);
    float d = distG[base + kk];
    dist[k] = d;
    unsigned int u = __float_as_uint(d);
    ukey[k] = u ^ (((unsigned int)((int)u >> 31)) | 0x80000000u);
    lmax = fmaxf(lmax, d);
  }
#pragma unroll
  for (int off = 32; off > 0; off >>= 1)
    lmax = fmaxf(lmax, __shfl_down(lmax, off, 64));
  if (lane == 0) redf[wid] = lmax;
  __syncthreads();                                             // B1
  const float dmax = fmaxf(fmaxf(redf[0], redf[1]), fmaxf(redf[2], redf[3]));
  for (int k = tid; k < NC_; k += 256) atomicAdd(&hist[ukey[k] >> 24], 1u);
  __syncthreads();                                             // B2
  if (wid == 0) {
    int s4 = (int)(hist[lane * 4] + hist[lane * 4 + 1] + hist[lane * 4 + 2] + hist[lane * 4 + 3]);
    int s = s4;
#pragma unroll
    for (int off = 1; off < 64; off <<= 1) {
      int o = __shfl_down(s, off, 64);
      if (lane + off < 64) s += o;
    }
    int above = s - s4;
    if (above < KS_ && s >= KS_) {
      int run = above;
#pragma unroll
      for (int bb = 3; bb >= 0; --bb) {
        int h = (int)hist[lane * 4 + bb];
        if (run + h >= KS_) { scal[0] = (unsigned int)(lane * 4 + bb); scal[1] = (unsigned int)run; break; }
        run += h;
      }
    }
  }
  __syncthreads();                                             // B3
  const unsigned int beta = scal[0];
  const int run = (int)scal[1];
  for (int h = tid; h < 256; h += 256) hist[h] = 0;
  __syncthreads();                                             // B4
  for (int k = tid; k < NC_; k += 256)
    if ((ukey[k] >> 24) == beta) atomicAdd(&hist[(ukey[k] >> 16) & 0xFFu], 1u);
  __syncthreads();                                             // B5
  if (wid == 0) {
    int s4 = (int)(hist[lane * 4] + hist[lane * 4 + 1] + hist[lane * 4 + 2] + hist[lane * 4 + 3]);
    int s = s4;
#pragma unroll
    for (int off = 1; off < 64; off <<= 1) {
      int o = __shfl_down(s, off, 64);
      if (lane + off < 64) s += o;
    }
    int above = run + s - s4;
    if (above < KS_ && run + s >= KS_) {
      int r2 = above;
#pragma unroll
      for (int bb = 3; bb >= 0; --bb) {
        int h = (int)hist[lane * 4 + bb];
        if (r2 + h >= KS_) { scal[4] = (unsigned int)(lane * 4 + bb); scal[5] = (unsigned int)r2; break; }
        r2 += h;
      }
    }
  }
  __syncthreads();                                             // B6
  const unsigned int beta2 = scal[4];
  const int run2 = (int)scal[5];
  const size_t outb = ((size_t)t * NQ_ + q) * KS_;
  float lsum = 0.f;
  for (int k = tid; k < NC_; k += 256) {
    unsigned int key = ukey[k];
    unsigned int bin = key >> 24;
    bool sel = false, bdry = false;
    if (bin > beta) sel = true;
    else if (bin == beta) {
      unsigned int b2 = (key >> 16) & 0xFFu;
      if (b2 > beta2) sel = true;
      else if (b2 == beta2) bdry = true;
    }
    if (sel) {
      unsigned int slot = atomicAdd(&scal[2], 1u);
      int aa = k / 27, bb = k - aa * 27;
      int ni = min(max(qi + aa - 13, 0), H_ - 1);
      int nj = min(max(qj + bb - 13, 0), W_ - 1);
      float wv = __expf(SCALE_ * (dist[k] - dmax));
      sel_n[outb + slot] = (ni << 7) | nj;
      sel_w[outb + slot] = wv;
      lsum += wv;
    } else if (bdry) {
      unsigned int pos = atomicAdd(&scal[3], 1u);
      if (pos < LCAP_) { lk[pos] = k; lkey[pos] = key; }
    }
  }
  __syncthreads();                                             // B7
  const int L = min((int)scal[3], LCAP_);
  for (int i = tid; i < L; i += 256) {
    unsigned int key = lkey[i];
    int k = lk[i];
    int cnt = run2;
    for (int m = 0; m < L; ++m)
      cnt += (int)((lkey[m] > key) || (lkey[m] == key && lk[m] < k));
    if (cnt < KS_) {
      unsigned int slot = atomicAdd(&scal[2], 1u);
      int aa = k / 27, bb = k - aa * 27;
      int ni = min(max(qi + aa - 13, 0), H_ - 1);
      int nj = min(max(qj + bb - 13, 0), W_ - 1);
      float wv = __expf(SCALE_ * (dist[k] - dmax));
      sel_n[outb + slot] = (ni << 7) | nj;
      sel_w[outb + slot] = wv;
      lsum += wv;
    }
  }
#pragma unroll
  for (int off = 32; off > 0; off >>= 1) lsum += __shfl_down(lsum, off, 64);
  __syncthreads();                                             // B8
  if (lane == 0) redf[wid] = lsum;
  __syncthreads();                                             // B9
  if (tid == 0) wsum_out[t * NQ_ + q] = (redf[0] + redf[1]) + (redf[2] + redf[3]);
}

// ---------------- weighted aggregation + fold (direct L2 gather) ------------
__global__ __launch_bounds__(256) void agg_kernel(
    const float4* __restrict__ v2cs, const int* __restrict__ sel_n,
    const float* __restrict__ sel_w, const float* __restrict__ wsum,
    float* __restrict__ Y) {
  __shared__ int s_ni[KS_], s_nj[KS_];
  __shared__ float s_w[KS_];
  const int tid = threadIdx.x;
  const int q = blockIdx.x, t = blockIdx.y;
  const int qi = (q >> 5) * S0_, qj = (q & 31) * S0_;
  const size_t base = ((size_t)t * NQ_ + q) * KS_;
  if (tid < KS_) {
    int n = sel_n[base + tid];
    s_ni[tid] = n >> 7;
    s_nj[tid] = n & 127;
    s_w[tid] = sel_w[base + tid] / wsum[t * NQ_ + q];
  }
  __syncthreads();
  const int cc = tid >> 6, lane = tid & 63;
  if (lane >= 49) return;
  const int r = lane / 7, s = lane - r * 7;
  const float4* src = v2cs + ((size_t)cc * T_ + t) * HW_;
  float4 acc = make_float4(0.f, 0.f, 0.f, 0.f);
#pragma unroll 4
  for (int k = 0; k < KS_; ++k) {
    int ri = min(s_ni[k] + r, H_ - 1);
    int ci = min(s_nj[k] + s, W_ - 1);
    float4 v = src[ri * W_ + ci];
    float w = s_w[k];
    acc.x = fmaf(w, v.x, acc.x);
    acc.y = fmaf(w, v.y, acc.y);
    acc.z = fmaf(w, v.z, acc.z);
    acc.w = fmaf(w, v.w, acc.w);
  }
  const int oi = min(qi + r, H_ - 1), oj = min(qj + s, W_ - 1);
  float* yb = Y + (((size_t)t * CI_ + cc * 4) * H_ + oi) * W_ + oj;
  atomicAdd(yb, acc.x);
  atomicAdd(yb + HW_, acc.y);
  atomicAdd(yb + 2 * HW_, acc.z);
  atomicAdd(yb + 3 * HW_, acc.w);
}

// ---------------- normalize by analytic fold counts -------------------------
__device__ __forceinline__ int cov_axis(int x) {
  int c = 0;
#pragma unroll
  for (int r = 0; r < 7; ++r) {
    if (x < H_ - 1) {
      int qb = x - r;
      c += (qb >= 0 && (qb & 3) == 0) ? 1 : 0;
    } else {
      c += (r >= 3) ? 1 : 0;
    }
  }
  return c;
}

__global__ void norm_kernel(float* __restrict__ Y) {
  int idx = blockIdx.x * blockDim.x + threadIdx.x;
  if (idx >= T_ * CI_ * HW_) return;
  int p = idx & (HW_ - 1);
  float z = (float)(cov_axis(p >> 7) * cov_axis(p & 127));
  Y[idx] /= z;
}

extern "C" void kernel_launch(void* const* d_in, const int* in_sizes, int n_in,
                              void* d_out, int out_size, void* d_ws, size_t ws_size,
                              hipStream_t stream) {
  const float* vid     = (const float*)d_in[0];
  const float* g_w     = (const float*)d_in[1];
  const float* g_b     = (const float*)d_in[2];
  const float* theta_w = (const float*)d_in[3];
  const float* theta_b = (const float*)d_in[4];
  float* Y = (float*)d_out;

  // workspace (floats): v1cs | v2cs | distG | sel_n | sel_w | wsum  (~24 MB)
  float* v1cs  = (float*)d_ws;
  float* v2cs  = v1cs + (size_t)4 * T_ * HW_ * 4;              // 1048576
  float* distG = v2cs + (size_t)4 * T_ * HW_ * 4;              // 1048576
  int*   sel_n = (int*)(distG + (size_t)T_ * NQ_ * NC_);       // 2985984
  float* sel_w = (float*)(sel_n + (size_t)T_ * NQ_ * KS_);     // 409600
  float* wsumv = sel_w + (size_t)T_ * NQ_ * KS_;               // 409600

  hipMemsetAsync(Y, 0, (size_t)out_size * sizeof(float), stream);

  conv3x3_kernel<<<dim3(64, 4, T_), 128, 0, stream>>>(vid, g_w, g_b, (float4*)v1cs);
  conv1x1_kernel<<<dim3(HW_ / 256, T_, 4), 256, 0, stream>>>(vid, theta_w, theta_b, (float4*)v2cs);
  dist_kernel<<<dim3(64, T_), 1024, 0, stream>>>((const float4*)v1cs, distG);
  select_kernel<<<dim3(NQ_, T_), 256, 0, stream>>>(distG, sel_n, sel_w, wsumv);
  agg_kernel<<<dim3(NQ_, T_), 256, 0, stream>>>((const float4*)v2cs, sel_n, sel_w, wsumv, Y);
  norm_kernel<<<(T_ * CI_ * HW_ + 255) / 256, 256, 0, stream>>>(Y);
}

// Round 15
// 261.370 us; speedup vs baseline: 1.3358x; 1.1041x over previous
//
#include <hip/hip_runtime.h>
#include <hip/hip_bf16.h>

#define T_ 4
#define C_ 64
#define H_ 128
#define W_ 128
#define CI_ 16
#define PS_ 7
#define NC_ 729       // 27*27 candidates per query
#define S0_ 4
#define KS_ 100
#define NQ_ 1024      // 32*32 queries per frame
#define SCALE_ 10.0f
#define HW_ (H_*W_)
#define RW_ 45        // 4x4-tile region dim (float4); 45%8=5 -> bank rotation
#define LCAP_ 768
#define CB_ 8         // conv3x3 channel batch (24 dwordx4 in flight)

typedef float v2f __attribute__((ext_vector_type(2)));
#if __has_builtin(__builtin_elementwise_fma)
#define VFMA(a, b, c) __builtin_elementwise_fma((a), (b), (c))
#else
#define VFMA(a, b, c) ((a) * (b) + (c))
#endif

// ---------------- conv 3x3, 64->16, BRANCH-FREE batched loads ---------------
__device__ __forceinline__ float4 colfix(float4 r, bool loB, bool hiB) {
  float4 o;
  o.x = loB ? 0.f : (hiB ? r.y : r.x);
  o.y = loB ? r.x : (hiB ? r.z : r.y);
  o.z = loB ? r.y : (hiB ? r.w : r.z);
  o.w = loB ? r.z : (hiB ? 0.f : r.w);
  return o;
}

__global__ __launch_bounds__(128, 1) void conv3x3_kernel(
    const float* __restrict__ vid, const float* __restrict__ gw,
    const float* __restrict__ gb, float4* __restrict__ v1cs) {
  __shared__ float wls[C_ * 9 * 4];   // [c][k][co]
  const int tid = threadIdx.x;
  const int g = blockIdx.y, t = blockIdx.z;
  for (int m = tid; m < C_ * 9 * 4; m += 128) {
    int co = m & 3, ck = m >> 2;
    wls[m] = gw[((size_t)(g * 4 + co) * C_) * 9 + ck];
  }
  __syncthreads();
  const int ti0 = (blockIdx.x >> 3) * 16, tj0 = (blockIdx.x & 7) * 16;
  const int u = tid >> 3, v = tid & 7;   // 16 rows x 8 col-pairs
  const int i = ti0 + u, j0 = tj0 + 2 * v;
  const int c0 = j0 - 1;
  const int c0c = min(max(c0, 0), W_ - 4);
  const bool loB = (c0 < 0), hiB = (c0 > W_ - 4);
  const int rm1 = max(i - 1, 0), rp1 = min(i + 1, H_ - 1);
  const float mk0 = (i > 0) ? 1.f : 0.f;
  const float mk2 = (i < H_ - 1) ? 1.f : 0.f;
  const int o0 = rm1 * W_ + c0c, o1 = i * W_ + c0c, o2 = rp1 * W_ + c0c;

  float accA[4], accB[4];
#pragma unroll
  for (int co = 0; co < 4; ++co) { accA[co] = gb[g * 4 + co]; accB[co] = gb[g * 4 + co]; }

  const float* vb = vid + ((size_t)t * C_) * HW_;
#pragma unroll 1
  for (int cb = 0; cb < C_; cb += CB_) {
    float4 r[CB_][3];
#pragma unroll
    for (int c = 0; c < CB_; ++c) {       // 24 UNCONDITIONAL loads -> in flight
      const float* p = vb + (size_t)(cb + c) * HW_;
      r[c][0] = *(const float4*)(p + o0);
      r[c][1] = *(const float4*)(p + o1);
      r[c][2] = *(const float4*)(p + o2);
    }
#pragma unroll
    for (int c = 0; c < CB_; ++c) {
      float4 f0 = colfix(r[c][0], loB, hiB);
      float4 f1 = colfix(r[c][1], loB, hiB);
      float4 f2 = colfix(r[c][2], loB, hiB);
      f0.x *= mk0; f0.y *= mk0; f0.z *= mk0; f0.w *= mk0;
      f2.x *= mk2; f2.y *= mk2; f2.z *= mk2; f2.w *= mk2;
      const float* wc = &wls[(cb + c) * 36];
      float e0[4] = {f0.x, f0.y, f0.z, f0.w};
      float e1[4] = {f1.x, f1.y, f1.z, f1.w};
      float e2[4] = {f2.x, f2.y, f2.z, f2.w};
#pragma unroll
      for (int kj = 0; kj < 3; ++kj) {
#pragma unroll
        for (int co = 0; co < 4; ++co) {
          accA[co] = fmaf(wc[(0 * 3 + kj) * 4 + co], e0[kj],     accA[co]);
          accB[co] = fmaf(wc[(0 * 3 + kj) * 4 + co], e0[kj + 1], accB[co]);
          accA[co] = fmaf(wc[(1 * 3 + kj) * 4 + co], e1[kj],     accA[co]);
          accB[co] = fmaf(wc[(1 * 3 + kj) * 4 + co], e1[kj + 1], accB[co]);
          accA[co] = fmaf(wc[(2 * 3 + kj) * 4 + co], e2[kj],     accA[co]);
          accB[co] = fmaf(wc[(2 * 3 + kj) * 4 + co], e2[kj + 1], accB[co]);
        }
      }
    }
  }
  const size_t o = ((size_t)g * T_ + t) * HW_ + i * W_ + j0;
  v1cs[o]     = make_float4(accA[0], accA[1], accA[2], accA[3]);
  v1cs[o + 1] = make_float4(accB[0], accB[1], accB[2], accB[3]);
}

// ---------------- conv 1x1, 64->16, chunk-major float4 output ----------------
__global__ __launch_bounds__(256, 1) void conv1x1_kernel(
    const float* __restrict__ vid, const float* __restrict__ tw,
    const float* __restrict__ tb, float4* __restrict__ v2cs) {
  __shared__ float w[C_ * 4];
  const int t = blockIdx.y, cc = blockIdx.z;
  for (int m = threadIdx.x; m < C_ * 4; m += 256) {
    int o = m & 3, c = m >> 2;
    w[m] = tw[(cc * 4 + o) * C_ + c];
  }
  __syncthreads();
  const int pix = blockIdx.x * 256 + threadIdx.x;
  float acc[4];
#pragma unroll
  for (int o = 0; o < 4; ++o) acc[o] = tb[cc * 4 + o];
  const float* vb = vid + ((size_t)t * C_) * HW_ + pix;
#pragma unroll 1
  for (int c0 = 0; c0 < C_; c0 += 16) {
    float x[16];
#pragma unroll
    for (int uu = 0; uu < 16; ++uu) x[uu] = vb[(size_t)(c0 + uu) * HW_];
#pragma unroll
    for (int uu = 0; uu < 16; ++uu)
#pragma unroll
      for (int o = 0; o < 4; ++o)
        acc[o] = fmaf(w[(c0 + uu) * 4 + o], x[uu], acc[o]);
  }
  v2cs[((size_t)cc * T_ + t) * HW_ + pix] = make_float4(acc[0], acc[1], acc[2], acc[3]);
}

// ---------------- dists: 4x4-query tile, packed v_pk_fma_f32 accumulators ---
__global__ __launch_bounds__(1024) void dist_kernel(
    const float4* __restrict__ v1cs, float* __restrict__ distG) {
  __shared__ float4 Rs[RW_ * RW_];
  const int tid = threadIdx.x;
  const int t = blockIdx.y;
  const int qi0 = (blockIdx.x >> 3) * 16, qj0 = (blockIdx.x & 7) * 16;
  const int w = tid >> 6, lane = tid & 63;
  const int di = (w >> 2) * 4, dj = (w & 3) * 4;
  const int qi = qi0 + di, qj = qj0 + dj;
  const int a_lo = max(13 - qi, 0), b_lo = max(13 - qj, 0);
  const int ai = lane >> 1, bg = lane & 1;
  const bool active = ai < 27;
  const int a = min(a_lo + ai, 26);
  const int bs = bg ? 13 : b_lo;

  v2f acc2[14];
#pragma unroll
  for (int j = 0; j < 14; ++j) acc2[j] = (v2f){0.f, 0.f};

#pragma unroll 1
  for (int cc = 0; cc < 4; ++cc) {
    __syncthreads();
    const float4* src = v1cs + ((size_t)cc * T_ + t) * HW_;
    for (int p = tid; p < RW_ * RW_; p += 1024) {
      int uu = p / RW_, vv = p - uu * RW_;
      int row = min(max(qi0 - 13 + uu, 0), H_ - 1);
      int col = min(max(qj0 - 13 + vv, 0), W_ - 1);
      Rs[p] = src[row * W_ + col];
    }
    __syncthreads();
    if (active) {
#pragma unroll 1
      for (int r = 0; r < 7; ++r) {
        v2f qlo[7], qhi[7];
        const float4* qrow = &Rs[(di + 13 + r) * RW_ + dj + 13];
#pragma unroll
        for (int s = 0; s < 7; ++s) {
          float4 qq = qrow[s];
          qlo[s] = (v2f){qq.x, qq.y};
          qhi[s] = (v2f){qq.z, qq.w};
        }
        const float4* crow = &Rs[(di + a + r) * RW_ + dj + bs];
#pragma unroll
        for (int y = 0; y < 20; ++y) {
          float4 vv = crow[y];
          v2f vlo = (v2f){vv.x, vv.y}, vhi = (v2f){vv.z, vv.w};
          const int s_lo = (y > 13) ? (y - 13) : 0;
          const int s_hi = (y < 6) ? y : 6;
#pragma unroll
          for (int s = s_lo; s <= s_hi; ++s) {
            int j = y - s;
            acc2[j] = VFMA(qlo[s], vlo, acc2[j]);
            acc2[j] = VFMA(qhi[s], vhi, acc2[j]);
          }
        }
      }
    }
  }
  if (active) {
    const int q = ((qi >> 2) << 5) + (qj >> 2);
    float* out = distG + ((size_t)t * NQ_ + q) * NC_ + a * 27 + bs;
#pragma unroll
    for (int j = 0; j < 14; ++j) out[j] = acc2[j].x + acc2[j].y;
  }
}

// ---------------- select: 2-level radix top-100, wave-primitive scans -------
__global__ __launch_bounds__(256) void select_kernel(
    const float* __restrict__ distG, int* __restrict__ sel_n,
    float* __restrict__ sel_w, float* __restrict__ wsum_out) {
  __shared__ float dist[NC_];
  __shared__ unsigned int ukey[NC_];
  __shared__ float redf[4];
  __shared__ unsigned int hist[256];
  __shared__ int lk[LCAP_];
  __shared__ unsigned int lkey[LCAP_];
  __shared__ unsigned int scal[6];   // 0=beta 1=run 2=cursor 3=listlen 4=beta2 5=run2

  const int tid = threadIdx.x;
  const int lane = tid & 63, wid = tid >> 6;
  const int q = blockIdx.x, t = blockIdx.y;
  const int qi = (q >> 5) * S0_, qj = (q & 31) * S0_;
  const int a_lo = max(13 - qi, 0), b_lo = max(13 - qj, 0);
  const size_t base = ((size_t)t * NQ_ + q) * NC_;

  for (int h = tid; h < 256; h += 256) hist[h] = 0;
  if (tid == 0) { scal[2] = 0; scal[3] = 0; }
  float lmax = -INFINITY;
  for (int k = tid; k < NC_; k += 256) {
    int aa = k / 27, bb = k - aa * 27;
    int kk = max(aa, a_lo) * 27 + max(bb, b_lo);
    float d = distG[base + kk];
    dist[k] = d;
    unsigned int u = __float_as_uint(d);
    ukey[k] = u ^ (((unsigned int)((int)u >> 31)) | 0x80000000u);
    lmax = fmaxf(lmax, d);
  }
#pragma unroll
  for (int off = 32; off > 0; off >>= 1)
    lmax = fmaxf(lmax, __shfl_down(lmax, off, 64));
  if (lane == 0) redf[wid] = lmax;
  __syncthreads();                                             // B1
  const float dmax = fmaxf(fmaxf(redf[0], redf[1]), fmaxf(redf[2], redf[3]));
  for (int k = tid; k < NC_; k += 256) atomicAdd(&hist[ukey[k] >> 24], 1u);
  __syncthreads();                                             // B2
  if (wid == 0) {
    int s4 = (int)(hist[lane * 4] + hist[lane * 4 + 1] + hist[lane * 4 + 2] + hist[lane * 4 + 3]);
    int s = s4;
#pragma unroll
    for (int off = 1; off < 64; off <<= 1) {
      int o = __shfl_down(s, off, 64);
      if (lane + off < 64) s += o;
    }
    int above = s - s4;
    if (above < KS_ && s >= KS_) {
      int run = above;
#pragma unroll
      for (int bb = 3; bb >= 0; --bb) {
        int h = (int)hist[lane * 4 + bb];
        if (run + h >= KS_) { scal[0] = (unsigned int)(lane * 4 + bb); scal[1] = (unsigned int)run; break; }
        run += h;
      }
    }
  }
  __syncthreads();                                             // B3
  const unsigned int beta = scal[0];
  const int run = (int)scal[1];
  for (int h = tid; h < 256; h += 256) hist[h] = 0;
  __syncthreads();                                             // B4
  for (int k = tid; k < NC_; k += 256)
    if ((ukey[k] >> 24) == beta) atomicAdd(&hist[(ukey[k] >> 16) & 0xFFu], 1u);
  __syncthreads();                                             // B5
  if (wid == 0) {
    int s4 = (int)(hist[lane * 4] + hist[lane * 4 + 1] + hist[lane * 4 + 2] + hist[lane * 4 + 3]);
    int s = s4;
#pragma unroll
    for (int off = 1; off < 64; off <<= 1) {
      int o = __shfl_down(s, off, 64);
      if (lane + off < 64) s += o;
    }
    int above = run + s - s4;
    if (above < KS_ && run + s >= KS_) {
      int r2 = above;
#pragma unroll
      for (int bb = 3; bb >= 0; --bb) {
        int h = (int)hist[lane * 4 + bb];
        if (r2 + h >= KS_) { scal[4] = (unsigned int)(lane * 4 + bb); scal[5] = (unsigned int)r2; break; }
        r2 += h;
      }
    }
  }
  __syncthreads();                                             // B6
  const unsigned int beta2 = scal[4];
  const int run2 = (int)scal[5];
  const size_t outb = ((size_t)t * NQ_ + q) * KS_;
  float lsum = 0.f;
  for (int k = tid; k < NC_; k += 256) {
    unsigned int key = ukey[k];
    unsigned int bin = key >> 24;
    bool sel = false, bdry = false;
    if (bin > beta) sel = true;
    else if (bin == beta) {
      unsigned int b2 = (key >> 16) & 0xFFu;
      if (b2 > beta2) sel = true;
      else if (b2 == beta2) bdry = true;
    }
    if (sel) {
      unsigned int slot = atomicAdd(&scal[2], 1u);
      int aa = k / 27, bb = k - aa * 27;
      int ni = min(max(qi + aa - 13, 0), H_ - 1);
      int nj = min(max(qj + bb - 13, 0), W_ - 1);
      float wv = __expf(SCALE_ * (dist[k] - dmax));
      sel_n[outb + slot] = (ni << 7) | nj;
      sel_w[outb + slot] = wv;
      lsum += wv;
    } else if (bdry) {
      unsigned int pos = atomicAdd(&scal[3], 1u);
      if (pos < LCAP_) { lk[pos] = k; lkey[pos] = key; }
    }
  }
  __syncthreads();                                             // B7
  const int L = min((int)scal[3], LCAP_);
  for (int i = tid; i < L; i += 256) {
    unsigned int key = lkey[i];
    int k = lk[i];
    int cnt = run2;
    for (int m = 0; m < L; ++m)
      cnt += (int)((lkey[m] > key) || (lkey[m] == key && lk[m] < k));
    if (cnt < KS_) {
      unsigned int slot = atomicAdd(&scal[2], 1u);
      int aa = k / 27, bb = k - aa * 27;
      int ni = min(max(qi + aa - 13, 0), H_ - 1);
      int nj = min(max(qj + bb - 13, 0), W_ - 1);
      float wv = __expf(SCALE_ * (dist[k] - dmax));
      sel_n[outb + slot] = (ni << 7) | nj;
      sel_w[outb + slot] = wv;
      lsum += wv;
    }
  }
#pragma unroll
  for (int off = 32; off > 0; off >>= 1) lsum += __shfl_down(lsum, off, 64);
  __syncthreads();                                             // B8
  if (lane == 0) redf[wid] = lsum;
  __syncthreads();                                             // B9
  if (tid == 0) wsum_out[t * NQ_ + q] = (redf[0] + redf[1]) + (redf[2] + redf[3]);
}

// ---------------- weighted aggregation + fold (4x4-tile LDS region) ---------
// 1024 threads = 16 waves = 16 queries sharing a 45x45 float4 region.
// L2 gather traffic (2.7 GB) -> coalesced staging (~33 MB) + LDS reads.
__global__ __launch_bounds__(1024) void agg_kernel(
    const float4* __restrict__ v2cs, const int* __restrict__ sel_n,
    const float* __restrict__ sel_w, const float* __restrict__ wsum,
    float* __restrict__ Y) {
  __shared__ float4 Rs[RW_ * RW_];
  __shared__ int s_off[16][KS_];
  __shared__ float s_w[16][KS_];
  const int tid = threadIdx.x;
  const int t = blockIdx.y;
  const int qi0 = (blockIdx.x >> 3) * 16, qj0 = (blockIdx.x & 7) * 16;
  const int w = tid >> 6, lane = tid & 63;
  const int di = (w >> 2) * 4, dj = (w & 3) * 4;
  const int qi = qi0 + di, qj = qj0 + dj;
  const int q = ((qi >> 2) << 5) + (qj >> 2);
  const size_t base = ((size_t)t * NQ_ + q) * KS_;
  const float inv = 1.0f / wsum[t * NQ_ + q];
  for (int k = lane; k < KS_; k += 64) {
    int n = sel_n[base + k];
    int ni = n >> 7, nj = n & 127;
    s_off[w][k] = (ni - qi0 + 13) * RW_ + (nj - qj0 + 13);
    s_w[w][k] = sel_w[base + k] * inv;
  }
  const int r = lane / 7, s = lane - r * 7;    // valid for lane < 49
  const int myo = r * RW_ + s;
  const int oi = min(qi + r, H_ - 1), oj = min(qj + s, W_ - 1);
#pragma unroll 1
  for (int cc = 0; cc < 4; ++cc) {
    __syncthreads();
    const float4* src = v2cs + ((size_t)cc * T_ + t) * HW_;
    for (int p = tid; p < RW_ * RW_; p += 1024) {
      int uu = p / RW_, vv = p - uu * RW_;
      int row = min(max(qi0 - 13 + uu, 0), H_ - 1);
      int col = min(max(qj0 - 13 + vv, 0), W_ - 1);
      Rs[p] = src[row * W_ + col];
    }
    __syncthreads();
    if (lane < 49) {
      float4 acc = make_float4(0.f, 0.f, 0.f, 0.f);
#pragma unroll 4
      for (int k = 0; k < KS_; ++k) {
        float wv = s_w[w][k];
        float4 v = Rs[s_off[w][k] + myo];
        acc.x = fmaf(wv, v.x, acc.x);
        acc.y = fmaf(wv, v.y, acc.y);
        acc.z = fmaf(wv, v.z, acc.z);
        acc.w = fmaf(wv, v.w, acc.w);
      }
      float* yb = Y + (((size_t)t * CI_ + cc * 4) * H_ + oi) * W_ + oj;
      atomicAdd(yb, acc.x);
      atomicAdd(yb + HW_, acc.y);
      atomicAdd(yb + 2 * HW_, acc.z);
      atomicAdd(yb + 3 * HW_, acc.w);
    }
  }
}

// ---------------- normalize by analytic fold counts -------------------------
__device__ __forceinline__ int cov_axis(int x) {
  int c = 0;
#pragma unroll
  for (int r = 0; r < 7; ++r) {
    if (x < H_ - 1) {
      int qb = x - r;
      c += (qb >= 0 && (qb & 3) == 0) ? 1 : 0;
    } else {
      c += (r >= 3) ? 1 : 0;
    }
  }
  return c;
}

__global__ void norm_kernel(float* __restrict__ Y) {
  int idx = blockIdx.x * blockDim.x + threadIdx.x;
  if (idx >= T_ * CI_ * HW_) return;
  int p = idx & (HW_ - 1);
  float z = (float)(cov_axis(p >> 7) * cov_axis(p & 127));
  Y[idx] /= z;
}

extern "C" void kernel_launch(void* const* d_in, const int* in_sizes, int n_in,
                              void* d_out, int out_size, void* d_ws, size_t ws_size,
                              hipStream_t stream) {
  const float* vid     = (const float*)d_in[0];
  const float* g_w     = (const float*)d_in[1];
  const float* g_b     = (const float*)d_in[2];
  const float* theta_w = (const float*)d_in[3];
  const float* theta_b = (const float*)d_in[4];
  float* Y = (float*)d_out;

  // workspace (floats): v1cs | v2cs | distG | sel_n | sel_w | wsum  (~24 MB)
  float* v1cs  = (float*)d_ws;
  float* v2cs  = v1cs + (size_t)4 * T_ * HW_ * 4;              // 1048576
  float* distG = v2cs + (size_t)4 * T_ * HW_ * 4;              // 1048576
  int*   sel_n = (int*)(distG + (size_t)T_ * NQ_ * NC_);       // 2985984
  float* sel_w = (float*)(sel_n + (size_t)T_ * NQ_ * KS_);     // 409600
  float* wsumv = sel_w + (size_t)T_ * NQ_ * KS_;               // 409600

  hipMemsetAsync(Y, 0, (size_t)out_size * sizeof(float), stream);

  conv3x3_kernel<<<dim3(64, 4, T_), 128, 0, stream>>>(vid, g_w, g_b, (float4*)v1cs);
  conv1x1_kernel<<<dim3(HW_ / 256, T_, 4), 256, 0, stream>>>(vid, theta_w, theta_b, (float4*)v2cs);
  dist_kernel<<<dim3(64, T_), 1024, 0, stream>>>((const float4*)v1cs, distG);
  select_kernel<<<dim3(NQ_, T_), 256, 0, stream>>>(distG, sel_n, sel_w, wsumv);
  agg_kernel<<<dim3(64, T_), 1024, 0, stream>>>((const float4*)v2cs, sel_n, sel_w, wsumv, Y);
  norm_kernel<<<(T_ * CI_ * HW_ + 255) / 256, 256, 0, stream>>>(Y);
}